// Round 8
// baseline (170.884 us; speedup 1.0000x reference)
//
#include <hip/hip_runtime.h>
#include <stdint.h>

typedef __attribute__((__ext_vector_type__(8))) __bf16 bf16x8;
typedef __attribute__((__ext_vector_type__(4))) float  f32x4;

// ---- workspace layout (bytes) ----
#define XT_OFF    0ul          // 16*64*64*256 bf16 = 33,554,432
#define WT_OFF    33554432ul   // 36*16384 bf16     =  1,179,648  [tap][s][co][ci64]
#define BEFF_OFF  34734080ul   // 256 f32
#define ZERO_OFF  34737152ul   // 256 B zeros
#define STATS_OFF 34737408ul   // 512 f32 (sum, sumsq per channel)

__device__ inline void gload_lds16(const void* g, void* l) {
  __builtin_amdgcn_global_load_lds((const __attribute__((address_space(1))) void*)g,
                                   (__attribute__((address_space(3))) void*)l,
                                   16, 0, 0);
}

// K1: Wt[(tap*4+s)*16384 + co*64 + cis] = alpha/16 * sum_{r,o} w[r*256+co][o*256+ci][tap]
__global__ void k_wred(const float* __restrict__ w, const float* __restrict__ bias,
                       const float* __restrict__ alpha_p, __bf16* __restrict__ Wt,
                       float* __restrict__ beff, float* __restrict__ zerob,
                       float* __restrict__ statsG) {
  const int co = blockIdx.x;    // 256
  const int ci = threadIdx.x;   // 256
  float a[9];
#pragma unroll
  for (int t = 0; t < 9; ++t) a[t] = 0.f;
#pragma unroll
  for (int r = 0; r < 2; ++r)
#pragma unroll
    for (int o = 0; o < 8; ++o) {
      const float* p = w + ((size_t)(r * 256 + co) * 2048 + (size_t)(o * 256 + ci)) * 9;
#pragma unroll
      for (int t = 0; t < 9; ++t) a[t] += p[t];
    }
  const float sc = alpha_p[0] * 0.0625f;      // alpha / (NORI*NROT)
  const int s = ci >> 6, cis = ci & 63;
#pragma unroll
  for (int t = 0; t < 9; ++t)
    Wt[(size_t)(t * 4 + s) * 16384 + co * 64 + cis] = (__bf16)(a[t] * sc);
  if (ci == 0) beff[co] = (bias[co] + bias[256 + co]) * 8.0f * sc;
  if (blockIdx.x == 0) {
    statsG[ci] = 0.f; statsG[256 + ci] = 0.f;
    if (ci < 64) zerob[ci] = 0.f;
  }
}

// K1b: x[b][ci][h][w] f32 -> xT[b][h][w][ci] bf16  (LDS-tiled transpose)
__global__ void k_xpose(const float* __restrict__ x, __bf16* __restrict__ xT) {
  __shared__ __bf16 lds[64 * 258];
  int bh = blockIdx.x;          // 16*64
  int b = bh >> 6, h = bh & 63;
  int t = threadIdx.x;          // 256
  int w = t & 63, cg = t >> 6;
  const float* xb = x + ((size_t)b * 16384 + h) * 64;   // + ci*4096 + w
#pragma unroll 4
  for (int cb = 0; cb < 256; cb += 4) {
    int ci = cb + cg;
    lds[w * 258 + ci] = (__bf16)xb[(size_t)ci * 4096 + w];
  }
  __syncthreads();
  const uint32_t* l32 = (const uint32_t*)lds;
  uint32_t* o32 = (uint32_t*)(xT + ((size_t)b * 64 + h) * 64 * 256);
  int c2 = t & 127, wg = t >> 7;              // 2 w per iter
  for (int w0 = 0; w0 < 64; w0 += 2) {
    int ww = w0 + wg;
    o32[ww * 128 + c2] = l32[ww * 129 + c2];
  }
}

// K2: implicit-GEMM conv + residual + fused BN stats.
// 256 blocks (1/CU), 512 threads = 8 waves (2m x 4n), wave tile 128x64.
// 36 phases = s(4 ci64) x tap(9), K=64/phase.
// KEY CHANGE (R8): B lives in REGISTERS (double-buffered bA/bB, prefetched one
// phase ahead via plain global loads from L2-resident Wt; compiler inserts
// precise counted vmcnt). LDS holds only the A slab (double-buffered).
// => NO barriers for 8 of 9 phases; waves free-run so LDS reads of one wave
// overlap MFMA bursts of the others. Only syncs: 3 s-boundary vmcnt(8)+barrier.
#define A_BYTES 51200            // 50 chunks * 1024 (396 pos * 128B, padded)

#define MFMAq(RH, AV, B, KO)                                                    \
  _Pragma("unroll")                                                             \
  for (int j = 0; j < 4; ++j) {                                                 \
    _Pragma("unroll")                                                           \
    for (int q = 0; q < 4; ++q)                                                 \
      acc[(RH) * 4 + q][j] =                                                    \
        __builtin_amdgcn_mfma_f32_16x16x32_bf16(AV[q], (B)[(KO) + j],           \
                                                acc[(RH) * 4 + q][j], 0, 0, 0); \
  }

__global__ __launch_bounds__(512, 2) void k_conv(
    const float* __restrict__ x, const __bf16* __restrict__ xT,
    const __bf16* __restrict__ Wt, const float* __restrict__ beff,
    const __bf16* __restrict__ zerob, float* __restrict__ out,
    float* __restrict__ statsG)
{
  __shared__ __align__(16) char lds[2 * A_BYTES + 2048];   // 104448 B
  const int bb   = blockIdx.x >> 4;
  const int ho0  = (blockIdx.x & 15) << 2;   // 4 output rows per block
  const int tid  = threadIdx.x;
  const int lane = tid & 63;
  const int wid  = tid >> 6;                 // 8 waves: 2 (m) x 4 (co)
  const int wr   = wid >> 2;                 // m half: rows ho0+wr*2+{0,1}
  const int wc   = wid & 3;                  // co quarter (64)
  const int l15  = lane & 15;

  f32x4 acc[8][4];
#pragma unroll
  for (int i = 0; i < 8; ++i)
#pragma unroll
    for (int j = 0; j < 4; ++j)
#pragma unroll
      for (int r = 0; r < 4; ++r) acc[i][j][r] = 0.f;

  const char* zb = (const char*)zerob;

  // per-lane byte offset of this lane's B fragment row inside a 32KB Wt tile:
  // co = wc*64 + j*16 + l15 (j via imm), ci8 = (lane>>4)*8 (+32 via imm)
  const int bregBase = (((wc << 6) + l15) << 7) + ((lane >> 4) << 4);

  // ---- load B tile for flat phase ph into 8 regs (j*2048 + kk*64 imm offsets)
  auto loadB = [&](int ph, bf16x8* dst) {
    const int s2 = ph / 9, tp = ph - s2 * 9;
    const char* wn = (const char*)Wt + ((size_t)(tp * 4 + s2) << 15) + bregBase;
#pragma unroll
    for (int kk = 0; kk < 2; ++kk)
#pragma unroll
      for (int j = 0; j < 4; ++j)
        dst[(kk << 2) + j] = *(const bf16x8*)(wn + (j << 11) + (kk << 6));
  };

  // ---- stage A slab for ci-block s into buf (s&1): slab[r=6][c=66][ci=64],
  // 128B/pos; 16B-slot swizzle phys = logical ^ (pos&7); linear LDS dest +
  // inverse-swizzled global source (G21).
  auto stageA = [&](int s) {
    const int ci0 = s << 6;
    char* buf = lds + (s & 1) * A_BYTES;
    for (int t = wid; t < 50; t += 8) {
      const int ch = (t << 3) + (lane >> 3);   // pos = r*66+c, 0..399
      const int r  = ch / 66;
      const int c  = ch - r * 66;
      const int ir = ho0 - 1 + r;              // image row
      const int ic = c - 1;                    // image col
      const int k  = (lane & 7) ^ (ch & 7);    // logical 16B slot (8 ci elems)
      const char* src;
      if (ch < 396 && ir >= 0 && ir < 64 && ic >= 0 && ic < 64)
        src = (const char*)(xT + ((((size_t)bb << 6) + ir) * 64 + ic) * 256 + ci0 + (k << 3));
      else
        src = zb + (k << 4);
      gload_lds16(src, buf + (t << 10));
    }
  };

  bf16x8 bA[8], bB[8];

  // one conv phase: prefetch B(p+1) into nxt, compute with cur
  auto phase = [&](int p, bf16x8* cur, bf16x8* nxt) {
    const int s2 = p / 9, tap = p - s2 * 9;
    if (p + 1 < 36) loadB(p + 1, nxt);
    if (tap == 0 && s2 < 3) stageA(s2 + 1);    // into buf (s2+1)&1, read-safe
    const char* slab = lds + (s2 & 1) * A_BYTES;
    const int dh = (tap >= 6) ? 2 : (tap >= 3 ? 1 : 0);
    const int dw = tap - dh * 3;
    const int pr0  = ((wr << 1) + dh) * 66 + l15 + dw;
    const int pr1  = pr0 + 66;
    const int cib  = (lane >> 4) << 4;
    const int ab00 = (((pr0 << 7) + cib) ^ ((pr0 & 7) << 4));
    const int ab01 = (((pr1 << 7) + cib) ^ ((pr1 & 7) << 4));
    const int ab10 = (((pr0 << 7) + cib + 64) ^ ((pr0 & 7) << 4));
    const int ab11 = (((pr1 << 7) + cib + 64) ^ ((pr1 & 7) << 4));

    bf16x8 a0[4], a1[4], a2[4], a3[4];
#pragma unroll
    for (int q = 0; q < 4; ++q) a0[q] = *(const bf16x8*)(slab + ab00 + (q << 11));
    __builtin_amdgcn_s_setprio(1);
    MFMAq(0, a0, cur, 0);
    __builtin_amdgcn_s_setprio(0);
#pragma unroll
    for (int q = 0; q < 4; ++q) a1[q] = *(const bf16x8*)(slab + ab01 + (q << 11));
    __builtin_amdgcn_s_setprio(1);
    MFMAq(1, a1, cur, 0);
    __builtin_amdgcn_s_setprio(0);
#pragma unroll
    for (int q = 0; q < 4; ++q) a2[q] = *(const bf16x8*)(slab + ab10 + (q << 11));
    __builtin_amdgcn_s_setprio(1);
    MFMAq(0, a2, cur, 4);
    __builtin_amdgcn_s_setprio(0);
#pragma unroll
    for (int q = 0; q < 4; ++q) a3[q] = *(const bf16x8*)(slab + ab11 + (q << 11));
    __builtin_amdgcn_s_setprio(1);
    MFMAq(1, a3, cur, 4);
    __builtin_amdgcn_s_setprio(0);

    if (tap == 8 && s2 < 3) {
      // only B(p+1)'s 8 loads may remain outstanding -> A(s2+1) landed
      asm volatile("s_waitcnt vmcnt(8)" ::: "memory");
      __builtin_amdgcn_s_barrier();
    }
  };

  // prologue: A(0) staged, B(0) in regs; allow B(0)'s 8 loads to stay in flight
  stageA(0);
  loadB(0, bA);
  asm volatile("s_waitcnt vmcnt(8)" ::: "memory");
  __builtin_amdgcn_s_barrier();

  for (int pp = 0; pp < 18; ++pp) {
    phase(2 * pp,     bA, bB);
    phase(2 * pp + 1, bB, bA);
  }

  // ---- epilogue: per-wave LDS transpose (coalesced IO) + fused BN stats
  __syncthreads();
  float* sw    = (float*)lds + wid * 2064;     // 16 co x 129 m floats per wave
  float* lstat = (float*)(lds + 2 * A_BYTES);  // 512 floats
  if (tid < 512) lstat[tid] = 0.f;
  __syncthreads();

  const int cl = lane & 15, ch4 = (lane >> 4) << 2;
  const int cc2 = lane >> 2, q2 = lane & 3;    // stats-reduction roles
#pragma unroll
  for (int j = 0; j < 4; ++j) {
#pragma unroll
    for (int i = 0; i < 8; ++i)
#pragma unroll
      for (int r = 0; r < 4; ++r)
        sw[cl * 129 + (i << 4) + ch4 + r] = acc[i][j][r];
    for (int cc = 0; cc < 16; ++cc) {
      const int co = (wc << 6) + (j << 4) + cc;
      const float be = beff[co];
#pragma unroll
      for (int half = 0; half < 2; ++half) {
        const float conv = sw[cc * 129 + (half << 6) + lane];
        const int ho = ho0 + (wr << 1) + half;
        const size_t oi = ((((size_t)bb << 8) + (size_t)co) << 12) + (ho << 6) + lane;
        const float v = x[oi] + conv + be;
        out[oi] = v;
        sw[cc * 129 + (half << 6) + lane] = v;   // same addr per lane: no race
      }
    }
    // per-thread partial over 32 m-values of one co, then 2-level shfl
    float r1 = 0.f, r2 = 0.f;
#pragma unroll
    for (int k = 0; k < 32; ++k) {
      const float vv = sw[cc2 * 129 + (q2 << 5) + k];
      r1 += vv; r2 += vv * vv;
    }
    r1 += __shfl_xor(r1, 1); r2 += __shfl_xor(r2, 1);
    r1 += __shfl_xor(r1, 2); r2 += __shfl_xor(r2, 2);
    if (q2 == 0) {
      const int co = (wc << 6) + (j << 4) + cc2;
      atomicAdd(&lstat[co], r1);
      atomicAdd(&lstat[256 + co], r2);
    }
  }
  __syncthreads();
  if (tid < 512) atomicAdd(&statsG[tid], lstat[tid]);
}

// K3: BN finalize (inline) + apply
__global__ void k_apply(float* __restrict__ out, const float* __restrict__ statsG,
                        const float* __restrict__ gamma, const float* __restrict__ beta) {
  size_t i = (size_t)blockIdx.x * 256 + threadIdx.x;   // float4 index
  int co = (int)((i >> 10) & 255);
  const float mean = statsG[co] * (1.f / 65536.f);
  const float var  = statsG[256 + co] * (1.f / 65536.f) - mean * mean;
  const float inv  = rsqrtf(var + 1e-5f);
  const float sc   = gamma[co] * inv;
  const float sh   = beta[co] - mean * sc;
  float4* p = (float4*)out;
  float4 v = p[i];
  v.x = v.x * sc + sh; v.y = v.y * sc + sh; v.z = v.z * sc + sh; v.w = v.w * sc + sh;
  p[i] = v;
}

extern "C" void kernel_launch(void* const* d_in, const int* in_sizes, int n_in,
                              void* d_out, int out_size, void* d_ws, size_t ws_size,
                              hipStream_t stream) {
  const float* x     = (const float*)d_in[0];
  const float* wall  = (const float*)d_in[1];
  const float* bias  = (const float*)d_in[2];
  const float* alpha = (const float*)d_in[3];
  const float* gamma = (const float*)d_in[4];
  const float* beta  = (const float*)d_in[5];
  float* out = (float*)d_out;

  char* ws = (char*)d_ws;
  __bf16* xT     = (__bf16*)(ws + XT_OFF);
  __bf16* Wt     = (__bf16*)(ws + WT_OFF);
  float*  beff   = (float*)(ws + BEFF_OFF);
  float*  zerob  = (float*)(ws + ZERO_OFF);
  float*  statsG = (float*)(ws + STATS_OFF);

  k_wred<<<256, 256, 0, stream>>>(wall, bias, alpha, Wt, beff, zerob, statsG);
  k_xpose<<<1024, 256, 0, stream>>>(x, xT);
  k_conv<<<256, 512, 0, stream>>>(x, xT, Wt, beff, (const __bf16*)zerob, out, statsG);
  k_apply<<<16384, 256, 0, stream>>>(out, statsG, gamma, beta);
}

// Round 9
// 169.947 us; speedup vs baseline: 1.0055x; 1.0055x over previous
//
#include <hip/hip_runtime.h>
#include <hip/hip_cooperative_groups.h>
#include <stdint.h>

typedef __attribute__((__ext_vector_type__(8))) __bf16 bf16x8;
typedef __attribute__((__ext_vector_type__(4))) float  f32x4;

// ---- workspace layout (bytes) ----
#define XT_OFF    0ul          // 16*64*64*256 bf16 = 33,554,432
#define WT_OFF    33554432ul   // 36*16384 bf16     =  1,179,648  [tap][s][co][ci64]
#define BEFF_OFF  34734080ul   // 256 f32
#define ZERO_OFF  34737152ul   // 256 B zeros
#define STATS_OFF 34737408ul   // 512 f32 (sum, sumsq per channel)

__device__ inline void gload_lds16(const void* g, void* l) {
  __builtin_amdgcn_global_load_lds((const __attribute__((address_space(1))) void*)g,
                                   (__attribute__((address_space(3))) void*)l,
                                   16, 0, 0);
}

// K1 (merged): blocks 0..255 = weight reduction; blocks 256..1279 = x transpose.
__global__ void k_prep(const float* __restrict__ w, const float* __restrict__ bias,
                       const float* __restrict__ alpha_p, __bf16* __restrict__ Wt,
                       float* __restrict__ beff, float* __restrict__ zerob,
                       float* __restrict__ statsG,
                       const float* __restrict__ x, __bf16* __restrict__ xT) {
  __shared__ __bf16 lds[64 * 258];
  if (blockIdx.x < 256) {
    // ---- Wt[(tap*4+s)*16384 + co*64 + cis] = alpha/16 * sum_{r,o} w[...]
    const int co = blockIdx.x;
    const int ci = threadIdx.x;   // 256
    float a[9];
#pragma unroll
    for (int t = 0; t < 9; ++t) a[t] = 0.f;
#pragma unroll
    for (int r = 0; r < 2; ++r)
#pragma unroll
      for (int o = 0; o < 8; ++o) {
        const float* p = w + ((size_t)(r * 256 + co) * 2048 + (size_t)(o * 256 + ci)) * 9;
#pragma unroll
        for (int t = 0; t < 9; ++t) a[t] += p[t];
      }
    const float sc = alpha_p[0] * 0.0625f;      // alpha / (NORI*NROT)
    const int s = ci >> 6, cis = ci & 63;
#pragma unroll
    for (int t = 0; t < 9; ++t)
      Wt[(size_t)(t * 4 + s) * 16384 + co * 64 + cis] = (__bf16)(a[t] * sc);
    if (ci == 0) beff[co] = (bias[co] + bias[256 + co]) * 8.0f * sc;
    if (blockIdx.x == 0) {
      statsG[ci] = 0.f; statsG[256 + ci] = 0.f;
      if (ci < 64) zerob[ci] = 0.f;
    }
  } else {
    // ---- x[b][ci][h][w] f32 -> xT[b][h][w][ci] bf16 (LDS-tiled transpose)
    int bh = blockIdx.x - 256;    // 16*64
    int b = bh >> 6, h = bh & 63;
    int t = threadIdx.x;          // 256
    int w2 = t & 63, cg = t >> 6;
    const float* xb = x + ((size_t)b * 16384 + h) * 64;   // + ci*4096 + w
#pragma unroll 4
    for (int cb = 0; cb < 256; cb += 4) {
      int ci = cb + cg;
      lds[w2 * 258 + ci] = (__bf16)xb[(size_t)ci * 4096 + w2];
    }
    __syncthreads();
    const uint32_t* l32 = (const uint32_t*)lds;
    uint32_t* o32 = (uint32_t*)(xT + ((size_t)b * 64 + h) * 64 * 256);
    int c2 = t & 127, wg = t >> 7;              // 2 w per iter
    for (int w0 = 0; w0 < 64; w0 += 2) {
      int ww = w0 + wg;
      o32[ww * 128 + c2] = l32[ww * 129 + c2];
    }
  }
}

// K2: implicit-GEMM conv + residual + fused BN stats + grid-sync + BN apply.
// 256 blocks (1/CU, cooperative), 1024 threads = 16 waves (4m x 4n), 4 w/SIMD.
// BM=256 (4 out rows x 64 w), N=256 co, 36 phases = s(4 ci64) x tap(9).
// R4 schedule (best measured): stageB(next) issue -> MFMA -> __syncthreads.
// Wave tile 64x64: acc[4][4] f32x4 (64 regs) -> 128 unified VGPR/wave.
// Epilogue: v = x+conv+beff kept in acc; stats atomics; grid.sync(); y = v*sc+sh.
#define A_BYTES 51200            // 50 chunks * 1024 (396 pos * 128B, padded)
#define B_BYTES 32768

__global__ __launch_bounds__(1024) void k_conv(
    const float* __restrict__ x, const __bf16* __restrict__ xT,
    const __bf16* __restrict__ Wt, const float* __restrict__ beff,
    const __bf16* __restrict__ zerob, float* __restrict__ out,
    float* __restrict__ statsG, const float* __restrict__ gamma,
    const float* __restrict__ beta)
{
  __shared__ __align__(16) char lds[A_BYTES + 2 * B_BYTES];   // 116736 B
  const int bb   = blockIdx.x >> 4;
  const int ho0  = (blockIdx.x & 15) << 2;   // 4 output rows per block
  const int tid  = threadIdx.x;
  const int lane = tid & 63;
  const int wid  = tid >> 6;                 // 16 waves: 4 (m) x 4 (co)
  const int wr   = wid >> 2;                 // image row ho0+wr
  const int wc   = wid & 3;                  // co quarter (64)

  f32x4 acc[4][4];
#pragma unroll
  for (int i = 0; i < 4; ++i)
#pragma unroll
    for (int j = 0; j < 4; ++j)
#pragma unroll
      for (int r = 0; r < 4; ++r) acc[i][j][r] = 0.f;

  const char* zb = (const char*)zerob;

  // hoisted B ds_read byte offsets (constant across phases)
  int boff[4][2];
#pragma unroll
  for (int j = 0; j < 4; ++j)
#pragma unroll
    for (int kk = 0; kk < 2; ++kk) {
      const int co     = (wc << 6) + (j << 4) + (lane & 15);
      const int ci_off = (kk << 5) + ((lane >> 4) << 3);
      boff[j][kk] = ((co << 7) + (ci_off << 1)) ^ ((co & 7) << 4);
    }
  // B stage per-lane source offset within a contiguous 32KB Wt phase-tile
  const int bl = lane >> 3;
  const int bsrcLane = (bl << 7) + (((lane & 7) ^ (bl & 7)) << 4);

  // ---- stage A slab for ci-block s: slab[r=6][c=66][ci=64] bf16, 128B/pos.
  // 16B-slot swizzle: phys_slot = logical_slot ^ (pos&7); linear LDS dest +
  // inverse-swizzled global source (G21).
  auto stageA = [&](int s) {
    const int ci0 = s << 6;
    for (int t = wid; t < 50; t += 16) {
      const int ch = (t << 3) + (lane >> 3);   // pos = r*66+c, 0..399
      const int r  = ch / 66;
      const int c  = ch - r * 66;
      const int ir = ho0 - 1 + r;              // image row
      const int ic = c - 1;                    // image col
      const int k  = (lane & 7) ^ (ch & 7);    // logical 16B slot (8 ci elems)
      const char* src;
      if (ch < 396 && ir >= 0 && ir < 64 && ic >= 0 && ic < 64)
        src = (const char*)(xT + ((((size_t)bb << 6) + ir) * 64 + ic) * 256 + ci0 + (k << 3));
      else
        src = zb + (k << 4);
      gload_lds16(src, lds + (t << 10));
    }
  };

  // ---- stage B tile (2 loads per wave) for phase (s,tap) into buffer bi.
  // Wt layout [tap][s][co][ci]: contiguous 32KB source block per phase.
  auto stageB = [&](int bi, int s2, int tp) {
    char* buf = lds + A_BYTES + bi * B_BYTES;
    const char* wsrc = (const char*)Wt + ((size_t)(tp * 4 + s2) << 15) + bsrcLane;
    gload_lds16(wsrc + (wid << 10), buf + (wid << 10));
    gload_lds16(wsrc + ((wid + 16) << 10), buf + ((wid + 16) << 10));
  };

  stageA(0);
  stageB(0, 0, 0);
  __syncthreads();

  int pb = 0;
  for (int s = 0; s < 4; ++s) {
    for (int tap = 0; tap < 9; ++tap) {
      const int p = s * 9 + tap;
      if (p + 1 < 36) {
        int ntap = tap + 1, ns = s;
        if (ntap == 9) { ntap = 0; ++ns; }
        stageB(pb ^ 1, ns, ntap);
      }
      const int dh = (tap >= 6) ? 2 : (tap >= 3 ? 1 : 0);
      const int dw = tap - dh * 3;
      const char* Bb = lds + A_BYTES + pb * B_BYTES;
      __builtin_amdgcn_s_setprio(1);
#pragma unroll
      for (int kk = 0; kk < 2; ++kk) {
        const int ci_off = (kk << 5) + ((lane >> 4) << 3);
        bf16x8 av[4];
#pragma unroll
        for (int i = 0; i < 4; ++i) {
          const int pos = (wr + dh) * 66 + (i << 4) + (lane & 15) + dw;
          const int off = ((pos << 7) + (ci_off << 1)) ^ ((pos & 7) << 4);
          av[i] = *(const bf16x8*)(lds + off);
        }
#pragma unroll
        for (int j = 0; j < 4; ++j) {
          const bf16x8 bv = *(const bf16x8*)(Bb + boff[j][kk]);
#pragma unroll
          for (int i = 0; i < 4; ++i)
            acc[i][j] = __builtin_amdgcn_mfma_f32_16x16x32_bf16(av[i], bv, acc[i][j], 0, 0, 0);
        }
      }
      __builtin_amdgcn_s_setprio(0);
      __syncthreads();                         // drains this phase's staging
      if (tap == 8 && s < 3) {                 // restage A (single-buffered)
        stageA(s + 1);
        __syncthreads();
      }
      pb ^= 1;
    }
  }

  // ---- epilogue phase 1: transpose, v = x+conv+beff (kept in acc), stats
  __syncthreads();
  float* sw    = (float*)lds + wid * 1040;     // 16 co x 65 floats per wave
  float* lstat = (float*)(lds + 112640);       // 512 floats
  if (tid < 512) lstat[tid] = 0.f;
  __syncthreads();

  const int cl = lane & 15, ch4 = (lane >> 4) << 2;
  const int ho = ho0 + wr;
  const int cc2 = lane >> 2, q2 = lane & 3;    // stats-reduction roles
#pragma unroll
  for (int j = 0; j < 4; ++j) {
#pragma unroll
    for (int i = 0; i < 4; ++i)
#pragma unroll
      for (int r = 0; r < 4; ++r)
        sw[cl * 65 + (i << 4) + ch4 + r] = acc[i][j][r];
    asm volatile("s_waitcnt lgkmcnt(0)" ::: "memory");
#pragma unroll
    for (int cc = 0; cc < 16; ++cc) {
      const int co = (wc << 6) + (j << 4) + cc;
      const float conv = sw[cc * 65 + lane];
      const size_t oi = ((((size_t)bb << 8) + (size_t)co) << 12) + (ho << 6) + lane;
      const float v = x[oi] + conv + beff[co];
      acc[cc >> 2][j][cc & 3] = v;             // keep v for post-sync apply
      sw[cc * 65 + lane] = v;                  // same addr per lane: no race
    }
    asm volatile("s_waitcnt lgkmcnt(0)" ::: "memory");
    // per-thread partial over 16 w-values of one co, then 2-level shfl
    float r1 = 0.f, r2 = 0.f;
#pragma unroll
    for (int k = 0; k < 16; ++k) {
      const float vv = sw[cc2 * 65 + (q2 << 4) + k];
      r1 += vv; r2 += vv * vv;
    }
    r1 += __shfl_xor(r1, 1); r2 += __shfl_xor(r2, 1);
    r1 += __shfl_xor(r1, 2); r2 += __shfl_xor(r2, 2);
    if (q2 == 0) {
      const int co = (wc << 6) + (j << 4) + cc2;
      atomicAdd(&lstat[co], r1);
      atomicAdd(&lstat[256 + co], r2);
    }
    asm volatile("s_waitcnt lgkmcnt(0)" ::: "memory");  // reads done before next j
  }
  __syncthreads();
  if (tid < 512) atomicAdd(&statsG[tid], lstat[tid]);

  // ---- grid-wide sync: all stats atomics visible
  cooperative_groups::this_grid().sync();

  // ---- epilogue phase 2: per-block scale/shift, then y = v*sc+sh
  if (tid < 256) {
    const float mean = statsG[tid] * (1.f / 65536.f);
    const float var  = statsG[256 + tid] * (1.f / 65536.f) - mean * mean;
    const float inv  = rsqrtf(var + 1e-5f);
    const float sc   = gamma[tid] * inv;
    lstat[tid]       = sc;
    lstat[256 + tid] = beta[tid] - mean * sc;
  }
  __syncthreads();
#pragma unroll
  for (int j = 0; j < 4; ++j) {
#pragma unroll
    for (int cc = 0; cc < 16; ++cc) {
      const int co = (wc << 6) + (j << 4) + cc;
      const size_t oi = ((((size_t)bb << 8) + (size_t)co) << 12) + (ho << 6) + lane;
      out[oi] = acc[cc >> 2][j][cc & 3] * lstat[co] + lstat[256 + co];
    }
  }
}

extern "C" void kernel_launch(void* const* d_in, const int* in_sizes, int n_in,
                              void* d_out, int out_size, void* d_ws, size_t ws_size,
                              hipStream_t stream) {
  const float* x     = (const float*)d_in[0];
  const float* wall  = (const float*)d_in[1];
  const float* bias  = (const float*)d_in[2];
  const float* alpha = (const float*)d_in[3];
  const float* gamma = (const float*)d_in[4];
  const float* beta  = (const float*)d_in[5];
  float* out = (float*)d_out;

  char* ws = (char*)d_ws;
  __bf16* xT     = (__bf16*)(ws + XT_OFF);
  __bf16* Wt     = (__bf16*)(ws + WT_OFF);
  float*  beff   = (float*)(ws + BEFF_OFF);
  float*  zerob  = (float*)(ws + ZERO_OFF);
  float*  statsG = (float*)(ws + STATS_OFF);

  k_prep<<<1280, 256, 0, stream>>>(wall, bias, alpha, Wt, beff, zerob, statsG, x, xT);

  const __bf16* xTc = xT;
  const __bf16* Wtc = Wt;
  const float*  beffc = beff;
  const __bf16* zbc = (const __bf16*)zerob;
  void* args[] = {(void*)&x, (void*)&xTc, (void*)&Wtc, (void*)&beffc,
                  (void*)&zbc, (void*)&out, (void*)&statsG,
                  (void*)&gamma, (void*)&beta};
  hipLaunchCooperativeKernel((const void*)k_conv, dim3(256), dim3(1024),
                             args, 0, stream);
}

// Round 10
// 143.561 us; speedup vs baseline: 1.1903x; 1.1838x over previous
//
#include <hip/hip_runtime.h>
#include <hip/hip_cooperative_groups.h>
#include <stdint.h>

typedef __attribute__((__ext_vector_type__(8))) __bf16 bf16x8;
typedef __attribute__((__ext_vector_type__(4))) float  f32x4;

// ---- workspace layout (bytes) ----
#define XT_OFF    0ul          // 16*64*64*256 bf16 = 33,554,432
#define WT_OFF    33554432ul   // 36*16384 bf16     =  1,179,648  [tap][s][co][ci64]
#define BEFF_OFF  34734080ul   // 256 f32
#define ZERO_OFF  34737152ul   // 256 B zeros
#define STATS_OFF 34737408ul   // 512 f32 (sum, sumsq per channel)

__device__ inline void gload_lds16(const void* g, void* l) {
  __builtin_amdgcn_global_load_lds((const __attribute__((address_space(1))) void*)g,
                                   (__attribute__((address_space(3))) void*)l,
                                   16, 0, 0);
}

// K1 (merged): blocks 0..255 = weight reduction; blocks 256..1279 = x transpose.
__global__ void k_prep(const float* __restrict__ w, const float* __restrict__ bias,
                       const float* __restrict__ alpha_p, __bf16* __restrict__ Wt,
                       float* __restrict__ beff, float* __restrict__ zerob,
                       float* __restrict__ statsG,
                       const float* __restrict__ x, __bf16* __restrict__ xT) {
  __shared__ __bf16 lds[64 * 258];
  if (blockIdx.x < 256) {
    const int co = blockIdx.x;
    const int ci = threadIdx.x;   // 256
    float a[9];
#pragma unroll
    for (int t = 0; t < 9; ++t) a[t] = 0.f;
#pragma unroll
    for (int r = 0; r < 2; ++r)
#pragma unroll
      for (int o = 0; o < 8; ++o) {
        const float* p = w + ((size_t)(r * 256 + co) * 2048 + (size_t)(o * 256 + ci)) * 9;
#pragma unroll
        for (int t = 0; t < 9; ++t) a[t] += p[t];
      }
    const float sc = alpha_p[0] * 0.0625f;      // alpha / (NORI*NROT)
    const int s = ci >> 6, cis = ci & 63;
#pragma unroll
    for (int t = 0; t < 9; ++t)
      Wt[(size_t)(t * 4 + s) * 16384 + co * 64 + cis] = (__bf16)(a[t] * sc);
    if (ci == 0) beff[co] = (bias[co] + bias[256 + co]) * 8.0f * sc;
    if (blockIdx.x == 0) {
      statsG[ci] = 0.f; statsG[256 + ci] = 0.f;
      if (ci < 64) zerob[ci] = 0.f;
    }
  } else {
    // ---- x[b][ci][h][w] f32 -> xT[b][h][w][ci] bf16 (LDS-tiled transpose)
    int bh = blockIdx.x - 256;    // 16*64
    int b = bh >> 6, h = bh & 63;
    int t = threadIdx.x;          // 256
    int w2 = t & 63, cg = t >> 6;
    const float* xb = x + ((size_t)b * 16384 + h) * 64;   // + ci*4096 + w
#pragma unroll 4
    for (int cb = 0; cb < 256; cb += 4) {
      int ci = cb + cg;
      lds[w2 * 258 + ci] = (__bf16)xb[(size_t)ci * 4096 + w2];
    }
    __syncthreads();
    const uint32_t* l32 = (const uint32_t*)lds;
    uint32_t* o32 = (uint32_t*)(xT + ((size_t)b * 64 + h) * 64 * 256);
    int c2 = t & 127, wg = t >> 7;              // 2 w per iter
    for (int w0 = 0; w0 < 64; w0 += 2) {
      int ww = w0 + wg;
      o32[ww * 128 + c2] = l32[ww * 129 + c2];
    }
  }
}

// K2: implicit-GEMM conv + residual + BN stats + grid-sync + BN apply (fused).
// 256 blocks (1/CU, cooperative), 1024 threads = 16 waves (4m x 4n), 4 w/SIMD.
// Main loop = R4 (best measured): stageB(next) -> MFMA -> __syncthreads.
// Epilogue v=x+conv+beff parked in LDS as bf16 (NOT registers: R9's spill) ->
// in-register stats (shfl_xor 16/32 over the acc fragment's co-partition) ->
// grid.sync -> y = v*sc+sh, out written once.
#define A_BYTES 51200            // 50 chunks * 1024 (396 pos * 128B, padded)
#define B_BYTES 32768
#define VLDS_BYTES 131072        // 256 co * 4 rows * 64 w * 2B

__global__ __launch_bounds__(1024) void k_conv(
    const float* __restrict__ x, const __bf16* __restrict__ xT,
    const __bf16* __restrict__ Wt, const float* __restrict__ beff,
    const __bf16* __restrict__ zerob, float* __restrict__ out,
    float* __restrict__ statsG, const float* __restrict__ gamma,
    const float* __restrict__ beta)
{
  // union: main loop uses A(51200)+2B(65536)=116736; epilogue uses v(131072)+lstat
  __shared__ __align__(16) char lds[VLDS_BYTES + 2048];   // 133120 B
  const int bb   = blockIdx.x >> 4;
  const int ho0  = (blockIdx.x & 15) << 2;   // 4 output rows per block
  const int tid  = threadIdx.x;
  const int lane = tid & 63;
  const int wid  = tid >> 6;                 // 16 waves: 4 (m) x 4 (co)
  const int wr   = wid >> 2;                 // image row ho0+wr
  const int wc   = wid & 3;                  // co quarter (64)

  f32x4 acc[4][4];
#pragma unroll
  for (int i = 0; i < 4; ++i)
#pragma unroll
    for (int j = 0; j < 4; ++j)
#pragma unroll
      for (int r = 0; r < 4; ++r) acc[i][j][r] = 0.f;

  const char* zb = (const char*)zerob;

  // hoisted B ds_read byte offsets (constant across phases)
  int boff[4][2];
#pragma unroll
  for (int j = 0; j < 4; ++j)
#pragma unroll
    for (int kk = 0; kk < 2; ++kk) {
      const int co     = (wc << 6) + (j << 4) + (lane & 15);
      const int ci_off = (kk << 5) + ((lane >> 4) << 3);
      boff[j][kk] = ((co << 7) + (ci_off << 1)) ^ ((co & 7) << 4);
    }
  // B stage per-lane source offset within a contiguous 32KB Wt phase-tile
  const int bl = lane >> 3;
  const int bsrcLane = (bl << 7) + (((lane & 7) ^ (bl & 7)) << 4);

  // ---- stage A slab for ci-block s: slab[r=6][c=66][ci=64] bf16, 128B/pos.
  auto stageA = [&](int s) {
    const int ci0 = s << 6;
    for (int t = wid; t < 50; t += 16) {
      const int ch = (t << 3) + (lane >> 3);   // pos = r*66+c, 0..399
      const int r  = ch / 66;
      const int c  = ch - r * 66;
      const int ir = ho0 - 1 + r;              // image row
      const int ic = c - 1;                    // image col
      const int k  = (lane & 7) ^ (ch & 7);    // logical 16B slot (8 ci elems)
      const char* src;
      if (ch < 396 && ir >= 0 && ir < 64 && ic >= 0 && ic < 64)
        src = (const char*)(xT + ((((size_t)bb << 6) + ir) * 64 + ic) * 256 + ci0 + (k << 3));
      else
        src = zb + (k << 4);
      gload_lds16(src, lds + (t << 10));
    }
  };

  // ---- stage B tile (2 loads per wave) for phase (s,tap) into buffer bi.
  auto stageB = [&](int bi, int s2, int tp) {
    char* buf = lds + A_BYTES + bi * B_BYTES;
    const char* wsrc = (const char*)Wt + ((size_t)(tp * 4 + s2) << 15) + bsrcLane;
    gload_lds16(wsrc + (wid << 10), buf + (wid << 10));
    gload_lds16(wsrc + ((wid + 16) << 10), buf + ((wid + 16) << 10));
  };

  stageA(0);
  stageB(0, 0, 0);
  __syncthreads();

  int pb = 0;
  for (int s = 0; s < 4; ++s) {
    for (int tap = 0; tap < 9; ++tap) {
      const int p = s * 9 + tap;
      if (p + 1 < 36) {
        int ntap = tap + 1, ns = s;
        if (ntap == 9) { ntap = 0; ++ns; }
        stageB(pb ^ 1, ns, ntap);
      }
      const int dh = (tap >= 6) ? 2 : (tap >= 3 ? 1 : 0);
      const int dw = tap - dh * 3;
      const char* Bb = lds + A_BYTES + pb * B_BYTES;
      __builtin_amdgcn_s_setprio(1);
#pragma unroll
      for (int kk = 0; kk < 2; ++kk) {
        const int ci_off = (kk << 5) + ((lane >> 4) << 3);
        bf16x8 av[4];
#pragma unroll
        for (int i = 0; i < 4; ++i) {
          const int pos = (wr + dh) * 66 + (i << 4) + (lane & 15) + dw;
          const int off = ((pos << 7) + (ci_off << 1)) ^ ((pos & 7) << 4);
          av[i] = *(const bf16x8*)(lds + off);
        }
#pragma unroll
        for (int j = 0; j < 4; ++j) {
          const bf16x8 bv = *(const bf16x8*)(Bb + boff[j][kk]);
#pragma unroll
          for (int i = 0; i < 4; ++i)
            acc[i][j] = __builtin_amdgcn_mfma_f32_16x16x32_bf16(av[i], bv, acc[i][j], 0, 0, 0);
        }
      }
      __builtin_amdgcn_s_setprio(0);
      __syncthreads();                         // drains this phase's staging
      if (tap == 8 && s < 3) {                 // restage A (single-buffered)
        stageA(s + 1);
        __syncthreads();
      }
      pb ^= 1;
    }
  }

  // ---- epilogue phase 1: v = x+conv+beff -> vlds (bf16) + in-register stats
  __syncthreads();                             // main loop fully done; LDS reusable
  float* lstat = (float*)(lds + VLDS_BYTES);   // 512 floats
  if (tid < 512) lstat[tid] = 0.f;
  __syncthreads();

  const int l15 = lane & 15;
  const int wq  = lane >> 4;                   // 0..3 (w quad group)
  const int ho  = ho0 + wr;
#pragma unroll
  for (int j = 0; j < 4; ++j) {
    const int co = (wc << 6) + (j << 4) + l15;
    const float be = beff[co];
    const size_t xbase = ((((size_t)bb << 8) + (size_t)co) << 12) + (ho << 6);
    float r1 = 0.f, r2 = 0.f;
#pragma unroll
    for (int i = 0; i < 4; ++i) {
      const int w0 = (i << 4) + (wq << 2);
      const float4 xv = *(const float4*)(x + xbase + w0);
      float v0 = acc[i][j][0] + xv.x + be;
      float v1 = acc[i][j][1] + xv.y + be;
      float v2 = acc[i][j][2] + xv.z + be;
      float v3 = acc[i][j][3] + xv.w + be;
      r1 += v0 + v1 + v2 + v3;
      r2 += v0 * v0 + v1 * v1 + v2 * v2 + v3 * v3;
      // pack 4 bf16 and store 8B to vlds[co][wr][w0..w0+3], XOR-swizzled
      union { __bf16 h[4]; uint64_t u; } pk;
      pk.h[0] = (__bf16)v0; pk.h[1] = (__bf16)v1;
      pk.h[2] = (__bf16)v2; pk.h[3] = (__bf16)v3;
      const int vb = (((co << 9) + (wr << 7) + (w0 << 1))) ^ ((co & 7) << 4);
      *(uint64_t*)(lds + vb) = pk.u;
    }
    // lanes {l, l+16, l+32, l+48} share co -> reduce over them
    r1 += __shfl_xor(r1, 16); r2 += __shfl_xor(r2, 16);
    r1 += __shfl_xor(r1, 32); r2 += __shfl_xor(r2, 32);
    if (lane < 16) {
      atomicAdd(&lstat[co], r1);
      atomicAdd(&lstat[256 + co], r2);
    }
  }
  __syncthreads();
  if (tid < 512) atomicAdd(&statsG[tid], lstat[tid]);

  // ---- grid-wide sync: all stats atomics visible
  cooperative_groups::this_grid().sync();

  // ---- per-block scale/shift, then y = v*sc+sh (out written once, coalesced)
  if (tid < 256) {
    const float mean = statsG[tid] * (1.f / 65536.f);
    const float var  = statsG[256 + tid] * (1.f / 65536.f) - mean * mean;
    const float inv  = rsqrtf(var + 1e-5f);
    const float sc   = gamma[tid] * inv;
    lstat[tid]       = sc;
    lstat[256 + tid] = beta[tid] - mean * sc;
  }
  __syncthreads();
#pragma unroll
  for (int it = 0; it < 16; ++it) {
    const int vi = (it << 12) + (tid << 2);    // 4 bf16 per thread per iter
    const int co = vi >> 8;
    const int rw = (vi >> 6) & 3;
    const int w0 = vi & 63;
    const int vb = ((vi << 1)) ^ ((co & 7) << 4);
    union { __bf16 h[4]; uint64_t u; } pk;
    pk.u = *(const uint64_t*)(lds + vb);
    const float sc = lstat[co], sh = lstat[256 + co];
    float4 y;
    y.x = (float)pk.h[0] * sc + sh;
    y.y = (float)pk.h[1] * sc + sh;
    y.z = (float)pk.h[2] * sc + sh;
    y.w = (float)pk.h[3] * sc + sh;
    const size_t oi = ((((size_t)bb << 8) + (size_t)co) << 12) + ((ho0 + rw) << 6) + w0;
    *(float4*)(out + oi) = y;
  }
}

extern "C" void kernel_launch(void* const* d_in, const int* in_sizes, int n_in,
                              void* d_out, int out_size, void* d_ws, size_t ws_size,
                              hipStream_t stream) {
  const float* x     = (const float*)d_in[0];
  const float* wall  = (const float*)d_in[1];
  const float* bias  = (const float*)d_in[2];
  const float* alpha = (const float*)d_in[3];
  const float* gamma = (const float*)d_in[4];
  const float* beta  = (const float*)d_in[5];
  float* out = (float*)d_out;

  char* ws = (char*)d_ws;
  __bf16* xT     = (__bf16*)(ws + XT_OFF);
  __bf16* Wt     = (__bf16*)(ws + WT_OFF);
  float*  beff   = (float*)(ws + BEFF_OFF);
  float*  zerob  = (float*)(ws + ZERO_OFF);
  float*  statsG = (float*)(ws + STATS_OFF);

  k_prep<<<1280, 256, 0, stream>>>(wall, bias, alpha, Wt, beff, zerob, statsG, x, xT);

  const __bf16* xTc = xT;
  const __bf16* Wtc = Wt;
  const float*  beffc = beff;
  const __bf16* zbc = (const __bf16*)zerob;
  void* args[] = {(void*)&x, (void*)&xTc, (void*)&Wtc, (void*)&beffc,
                  (void*)&zbc, (void*)&out, (void*)&statsG,
                  (void*)&gamma, (void*)&beta};
  hipLaunchCooperativeKernel((const void*)k_conv, dim3(256), dim3(1024),
                             args, 0, stream);
}

// Round 11
// 127.365 us; speedup vs baseline: 1.3417x; 1.1272x over previous
//
#include <hip/hip_runtime.h>
#include <stdint.h>

typedef __attribute__((__ext_vector_type__(8))) __bf16 bf16x8;
typedef __attribute__((__ext_vector_type__(4))) float  f32x4;

// ---- workspace layout (bytes) ----
#define XT_OFF    0ul          // 16*64*64*256 bf16 = 33,554,432
#define WT_OFF    33554432ul   // 36*16384 bf16     =  1,179,648  [tap][s][co][ci64]
#define BEFF_OFF  34734080ul   // 256 f32
#define ZERO_OFF  34737152ul   // 256 B zeros
#define STATS_OFF 34737408ul   // 512 f32 (sum, sumsq per channel)

__device__ inline void gload_lds16(const void* g, void* l) {
  __builtin_amdgcn_global_load_lds((const __attribute__((address_space(1))) void*)g,
                                   (__attribute__((address_space(3))) void*)l,
                                   16, 0, 0);
}

// K1: Wt[(tap*4+s)*16384 + co*64 + cis] = alpha/16 * sum_{r,o} w[r*256+co][o*256+ci][tap]
__global__ void k_wred(const float* __restrict__ w, const float* __restrict__ bias,
                       const float* __restrict__ alpha_p, __bf16* __restrict__ Wt,
                       float* __restrict__ beff, float* __restrict__ zerob,
                       float* __restrict__ statsG) {
  const int co = blockIdx.x;    // 256
  const int ci = threadIdx.x;   // 256
  float a[9];
#pragma unroll
  for (int t = 0; t < 9; ++t) a[t] = 0.f;
#pragma unroll
  for (int r = 0; r < 2; ++r)
#pragma unroll
    for (int o = 0; o < 8; ++o) {
      const float* p = w + ((size_t)(r * 256 + co) * 2048 + (size_t)(o * 256 + ci)) * 9;
#pragma unroll
      for (int t = 0; t < 9; ++t) a[t] += p[t];
    }
  const float sc = alpha_p[0] * 0.0625f;      // alpha / (NORI*NROT)
  const int s = ci >> 6, cis = ci & 63;
#pragma unroll
  for (int t = 0; t < 9; ++t)
    Wt[(size_t)(t * 4 + s) * 16384 + co * 64 + cis] = (__bf16)(a[t] * sc);
  if (ci == 0) beff[co] = (bias[co] + bias[256 + co]) * 8.0f * sc;
  if (blockIdx.x == 0) {
    statsG[ci] = 0.f; statsG[256 + ci] = 0.f;
    if (ci < 64) zerob[ci] = 0.f;
  }
}

// K1b: x[b][ci][h][w] f32 -> xT[b][h][w][ci] bf16  (LDS-tiled transpose)
__global__ void k_xpose(const float* __restrict__ x, __bf16* __restrict__ xT) {
  __shared__ __bf16 lds[64 * 258];
  int bh = blockIdx.x;          // 16*64
  int b = bh >> 6, h = bh & 63;
  int t = threadIdx.x;          // 256
  int w = t & 63, cg = t >> 6;
  const float* xb = x + ((size_t)b * 16384 + h) * 64;   // + ci*4096 + w
#pragma unroll 4
  for (int cb = 0; cb < 256; cb += 4) {
    int ci = cb + cg;
    lds[w * 258 + ci] = (__bf16)xb[(size_t)ci * 4096 + w];
  }
  __syncthreads();
  const uint32_t* l32 = (const uint32_t*)lds;
  uint32_t* o32 = (uint32_t*)(xT + ((size_t)b * 64 + h) * 64 * 256);
  int c2 = t & 127, wg = t >> 7;              // 2 w per iter
  for (int w0 = 0; w0 < 64; w0 += 2) {
    int ww = w0 + wg;
    o32[ww * 128 + c2] = l32[ww * 129 + c2];
  }
}

// K2: implicit-GEMM conv + residual + fused BN stats.
// 256 blocks (1/CU), 1024 threads = 16 waves (4m x 4n), wave tile 64x64, 4 w/SIMD.
// 36 phases = s(4 ci64) x tap(9), K=64/phase.
// R11: counted-vmcnt pipeline at 16 waves: 3 B buffers, depth-2 prefetch,
// per phase {issue stageB(p+2); compute(p); vmcnt(2); s_barrier} — B(p+1),
// B(p+2) loads stay in flight across the barrier (T4). vmcnt(0) only at the
// 3 A-restage boundaries and the tail. asm memory fences pin LDS ops to phases.
// Epilogue: v = x+conv+beff in fragment layout (f32 out write, 64B segments),
// stats fully in-register (shfl_xor 16/32), no LDS transpose.
#define A_BYTES 51200            // 50 chunks * 1024 (396 pos * 128B, padded)
#define B_BYTES 32768

__global__ __launch_bounds__(1024) void k_conv(
    const float* __restrict__ x, const __bf16* __restrict__ xT,
    const __bf16* __restrict__ Wt, const float* __restrict__ beff,
    const __bf16* __restrict__ zerob, float* __restrict__ out,
    float* __restrict__ statsG)
{
  __shared__ __align__(16) char lds[A_BYTES + 3 * B_BYTES + 2048];   // 151552 B
  const int bb   = blockIdx.x >> 4;
  const int ho0  = (blockIdx.x & 15) << 2;   // 4 output rows per block
  const int tid  = threadIdx.x;
  const int lane = tid & 63;
  const int wid  = tid >> 6;                 // 16 waves: 4 (m) x 4 (co)
  const int wr   = wid >> 2;                 // image row ho0+wr
  const int wc   = wid & 3;                  // co quarter (64)
  const int l15  = lane & 15;

  f32x4 acc[4][4];
#pragma unroll
  for (int i = 0; i < 4; ++i)
#pragma unroll
    for (int j = 0; j < 4; ++j)
#pragma unroll
      for (int r = 0; r < 4; ++r) acc[i][j][r] = 0.f;

  const char* zb = (const char*)zerob;

  // hoisted B ds_read byte offsets (constant across phases)
  int boff[4][2];
#pragma unroll
  for (int j = 0; j < 4; ++j)
#pragma unroll
    for (int kk = 0; kk < 2; ++kk) {
      const int co     = (wc << 6) + (j << 4) + l15;
      const int ci_off = (kk << 5) + ((lane >> 4) << 3);
      boff[j][kk] = ((co << 7) + (ci_off << 1)) ^ ((co & 7) << 4);
    }
  // B stage per-lane source offset within a contiguous 32KB Wt phase-tile
  const int bl = lane >> 3;
  const int bsrcLane = (bl << 7) + (((lane & 7) ^ (bl & 7)) << 4);

  // ---- stage A slab for ci-block s: slab[r=6][c=66][ci=64] bf16, 128B/pos.
  // 16B-slot swizzle: phys_slot = logical_slot ^ (pos&7); linear LDS dest +
  // inverse-swizzled global source (G21).
  auto stageA = [&](int s) {
    const int ci0 = s << 6;
    for (int t = wid; t < 50; t += 16) {
      const int ch = (t << 3) + (lane >> 3);   // pos = r*66+c, 0..399
      const int r  = ch / 66;
      const int c  = ch - r * 66;
      const int ir = ho0 - 1 + r;              // image row
      const int ic = c - 1;                    // image col
      const int k  = (lane & 7) ^ (ch & 7);    // logical 16B slot (8 ci elems)
      const char* src;
      if (ch < 396 && ir >= 0 && ir < 64 && ic >= 0 && ic < 64)
        src = (const char*)(xT + ((((size_t)bb << 6) + ir) * 64 + ic) * 256 + ci0 + (k << 3));
      else
        src = zb + (k << 4);
      gload_lds16(src, lds + (t << 10));
    }
  };

  // ---- stage B tile (2 loads per wave) for flat phase ph into buffer bi.
  // Wt layout [tap][s][co][ci]: contiguous 32KB source block per phase.
  auto stageB = [&](int ph, int bi) {
    char* buf = lds + A_BYTES + bi * B_BYTES;
    const int s2 = ph / 9, tp = ph - s2 * 9;
    const char* wsrc = (const char*)Wt + ((size_t)(tp * 4 + s2) << 15) + bsrcLane;
    gload_lds16(wsrc + (wid << 10), buf + (wid << 10));
    gload_lds16(wsrc + ((wid + 16) << 10), buf + ((wid + 16) << 10));
  };

  // prologue: A(0), B(0), B(1) staged and drained
  stageA(0);
  stageB(0, 0);
  stageB(1, 1);
  asm volatile("s_waitcnt vmcnt(0)" ::: "memory");
  __builtin_amdgcn_s_barrier();
  asm volatile("" ::: "memory");

  int s = 0, tap = 0, bcur = 0;
  for (int p = 0; p < 36; ++p) {
    if (p + 2 < 36) {
      int bnx = bcur + 2; if (bnx >= 3) bnx -= 3;
      stageB(p + 2, bnx);                      // issue BEFORE compute (T3)
    }
    const int dh = (tap >= 6) ? 2 : (tap >= 3 ? 1 : 0);
    const int dw = tap - dh * 3;
    const char* Bb = lds + A_BYTES + bcur * B_BYTES;
    __builtin_amdgcn_s_setprio(1);
#pragma unroll
    for (int kk = 0; kk < 2; ++kk) {
      const int ci_off = (kk << 5) + ((lane >> 4) << 3);
      bf16x8 av[4];
#pragma unroll
      for (int i = 0; i < 4; ++i) {
        const int pos = (wr + dh) * 66 + (i << 4) + l15 + dw;
        const int off = ((pos << 7) + (ci_off << 1)) ^ ((pos & 7) << 4);
        av[i] = *(const bf16x8*)(lds + off);
      }
#pragma unroll
      for (int j = 0; j < 4; ++j) {
        const bf16x8 bv = *(const bf16x8*)(Bb + boff[j][kk]);
#pragma unroll
        for (int i = 0; i < 4; ++i)
          acc[i][j] = __builtin_amdgcn_mfma_f32_16x16x32_bf16(av[i], bv, acc[i][j], 0, 0, 0);
      }
    }
    __builtin_amdgcn_s_setprio(0);

    if (tap == 8 && s < 3) {
      // s-boundary: drain everything (incl. B(p+2)), restage A, drain again.
      asm volatile("s_waitcnt vmcnt(0)" ::: "memory");
      __builtin_amdgcn_s_barrier();
      asm volatile("" ::: "memory");
      stageA(s + 1);
      asm volatile("s_waitcnt vmcnt(0)" ::: "memory");
      __builtin_amdgcn_s_barrier();
      asm volatile("" ::: "memory");
    } else if (p + 2 < 36) {
      // steady state: own B(p+2) 2 loads may stay in flight; B(p+1) landed.
      asm volatile("s_waitcnt vmcnt(2)" ::: "memory");
      __builtin_amdgcn_s_barrier();
      asm volatile("" ::: "memory");
    } else if (p < 35) {
      // tail (p==34): nothing new issued; drain so B(35) is landed.
      asm volatile("s_waitcnt vmcnt(0)" ::: "memory");
      __builtin_amdgcn_s_barrier();
      asm volatile("" ::: "memory");
    }
    if (++tap == 9) { tap = 0; ++s; }
    if (++bcur == 3) bcur = 0;
  }

  // ---- epilogue: v = x+conv+beff (fragment layout), out f32, in-reg stats
  __syncthreads();
  float* lstat = (float*)(lds + A_BYTES + 3 * B_BYTES);   // 512 floats
  if (tid < 512) lstat[tid] = 0.f;
  __syncthreads();

  const int wq = lane >> 4;                    // 0..3 (w quad group)
  const int ho = ho0 + wr;
#pragma unroll
  for (int j = 0; j < 4; ++j) {
    const int co = (wc << 6) + (j << 4) + l15;
    const float be = beff[co];
    const size_t base = ((((size_t)bb << 8) + (size_t)co) << 12) + (ho << 6);
    float r1 = 0.f, r2 = 0.f;
#pragma unroll
    for (int i = 0; i < 4; ++i) {
      const int w0 = (i << 4) + (wq << 2);
      const float4 xv = *(const float4*)(x + base + w0);
      float4 v;
      v.x = acc[i][j][0] + xv.x + be;
      v.y = acc[i][j][1] + xv.y + be;
      v.z = acc[i][j][2] + xv.z + be;
      v.w = acc[i][j][3] + xv.w + be;
      r1 += v.x + v.y + v.z + v.w;
      r2 += v.x * v.x + v.y * v.y + v.z * v.z + v.w * v.w;
      *(float4*)(out + base + w0) = v;
    }
    // lanes {l, l+16, l+32, l+48} share co -> reduce over wq
    r1 += __shfl_xor(r1, 16); r2 += __shfl_xor(r2, 16);
    r1 += __shfl_xor(r1, 32); r2 += __shfl_xor(r2, 32);
    if (lane < 16) {
      atomicAdd(&lstat[co], r1);
      atomicAdd(&lstat[256 + co], r2);
    }
  }
  __syncthreads();
  if (tid < 512) atomicAdd(&statsG[tid], lstat[tid]);
}

// K3: BN finalize (inline) + in-place apply
__global__ void k_apply(float* __restrict__ out, const float* __restrict__ statsG,
                        const float* __restrict__ gamma, const float* __restrict__ beta) {
  size_t i = (size_t)blockIdx.x * 256 + threadIdx.x;   // float4 index
  int co = (int)((i >> 10) & 255);
  const float mean = statsG[co] * (1.f / 65536.f);
  const float var  = statsG[256 + co] * (1.f / 65536.f) - mean * mean;
  const float inv  = rsqrtf(var + 1e-5f);
  const float sc   = gamma[co] * inv;
  const float sh   = beta[co] - mean * sc;
  float4* p = (float4*)out;
  float4 v = p[i];
  v.x = v.x * sc + sh; v.y = v.y * sc + sh; v.z = v.z * sc + sh; v.w = v.w * sc + sh;
  p[i] = v;
}

extern "C" void kernel_launch(void* const* d_in, const int* in_sizes, int n_in,
                              void* d_out, int out_size, void* d_ws, size_t ws_size,
                              hipStream_t stream) {
  const float* x     = (const float*)d_in[0];
  const float* wall  = (const float*)d_in[1];
  const float* bias  = (const float*)d_in[2];
  const float* alpha = (const float*)d_in[3];
  const float* gamma = (const float*)d_in[4];
  const float* beta  = (const float*)d_in[5];
  float* out = (float*)d_out;

  char* ws = (char*)d_ws;
  __bf16* xT     = (__bf16*)(ws + XT_OFF);
  __bf16* Wt     = (__bf16*)(ws + WT_OFF);
  float*  beff   = (float*)(ws + BEFF_OFF);
  float*  zerob  = (float*)(ws + ZERO_OFF);
  float*  statsG = (float*)(ws + STATS_OFF);

  k_wred<<<256, 256, 0, stream>>>(wall, bias, alpha, Wt, beff, zerob, statsG);
  k_xpose<<<1024, 256, 0, stream>>>(x, xT);
  k_conv<<<256, 1024, 0, stream>>>(x, xT, Wt, beff, (const __bf16*)zerob, out, statsG);
  k_apply<<<16384, 256, 0, stream>>>(out, statsG, gamma, beta);
}

// Round 12
// 126.684 us; speedup vs baseline: 1.3489x; 1.0054x over previous
//
#include <hip/hip_runtime.h>
#include <stdint.h>

typedef __attribute__((__ext_vector_type__(8))) __bf16 bf16x8;
typedef __attribute__((__ext_vector_type__(4))) float  f32x4;

// ---- workspace layout (bytes) ----
#define XT_OFF    0ul          // 16*64*64*256 bf16 = 33,554,432
#define WT_OFF    33554432ul   // 36*16384 bf16     =  1,179,648  [tap][s][co][ci64]
#define BEFF_OFF  34734080ul   // 256 f32
#define ZERO_OFF  34737152ul   // 256 B zeros
#define STATS_OFF 34737408ul   // 512 f32 (sum, sumsq per channel)
#define V_OFF     35651584ul   // 16M bf16 = 33,554,432 (v intermediate)
#define WS_NEED   (V_OFF + 33554432ul)

__device__ inline void gload_lds16(const void* g, void* l) {
  __builtin_amdgcn_global_load_lds((const __attribute__((address_space(1))) void*)g,
                                   (__attribute__((address_space(3))) void*)l,
                                   16, 0, 0);
}

// K1: Wt[(tap*4+s)*16384 + co*64 + cis] = alpha/16 * sum_{r,o} w[r*256+co][o*256+ci][tap]
__global__ void k_wred(const float* __restrict__ w, const float* __restrict__ bias,
                       const float* __restrict__ alpha_p, __bf16* __restrict__ Wt,
                       float* __restrict__ beff, float* __restrict__ zerob,
                       float* __restrict__ statsG) {
  const int co = blockIdx.x;    // 256
  const int ci = threadIdx.x;   // 256
  float a[9];
#pragma unroll
  for (int t = 0; t < 9; ++t) a[t] = 0.f;
#pragma unroll
  for (int r = 0; r < 2; ++r)
#pragma unroll
    for (int o = 0; o < 8; ++o) {
      const float* p = w + ((size_t)(r * 256 + co) * 2048 + (size_t)(o * 256 + ci)) * 9;
#pragma unroll
      for (int t = 0; t < 9; ++t) a[t] += p[t];
    }
  const float sc = alpha_p[0] * 0.0625f;      // alpha / (NORI*NROT)
  const int s = ci >> 6, cis = ci & 63;
#pragma unroll
  for (int t = 0; t < 9; ++t)
    Wt[(size_t)(t * 4 + s) * 16384 + co * 64 + cis] = (__bf16)(a[t] * sc);
  if (ci == 0) beff[co] = (bias[co] + bias[256 + co]) * 8.0f * sc;
  if (blockIdx.x == 0) {
    statsG[ci] = 0.f; statsG[256 + ci] = 0.f;
    if (ci < 64) zerob[ci] = 0.f;
  }
}

// K1b: x[b][ci][h][w] f32 -> xT[b][h][w][ci] bf16  (LDS-tiled transpose)
__global__ void k_xpose(const float* __restrict__ x, __bf16* __restrict__ xT) {
  __shared__ __bf16 lds[64 * 258];
  int bh = blockIdx.x;          // 16*64
  int b = bh >> 6, h = bh & 63;
  int t = threadIdx.x;          // 256
  int w = t & 63, cg = t >> 6;
  const float* xb = x + ((size_t)b * 16384 + h) * 64;   // + ci*4096 + w
#pragma unroll 4
  for (int cb = 0; cb < 256; cb += 4) {
    int ci = cb + cg;
    lds[w * 258 + ci] = (__bf16)xb[(size_t)ci * 4096 + w];
  }
  __syncthreads();
  const uint32_t* l32 = (const uint32_t*)lds;
  uint32_t* o32 = (uint32_t*)(xT + ((size_t)b * 64 + h) * 64 * 256);
  int c2 = t & 127, wg = t >> 7;              // 2 w per iter
  for (int w0 = 0; w0 < 64; w0 += 2) {
    int ww = w0 + wg;
    o32[ww * 128 + c2] = l32[ww * 129 + c2];
  }
}

// K2: implicit-GEMM conv + residual + fused BN stats (R11 main loop, unchanged).
// 256 blocks (1/CU), 1024 threads = 16 waves (4m x 4n), wave tile 64x64, 4 w/SIMD.
// Epilogue: v = x+conv+beff; stats in-register (f32, unrounded); v stored as
// bf16 to vout (32 MB) when use_v16, else f32 to out (fallback).
#define A_BYTES 51200            // 50 chunks * 1024 (396 pos * 128B, padded)
#define B_BYTES 32768

__global__ __launch_bounds__(1024) void k_conv(
    const float* __restrict__ x, const __bf16* __restrict__ xT,
    const __bf16* __restrict__ Wt, const float* __restrict__ beff,
    const __bf16* __restrict__ zerob, float* __restrict__ out,
    float* __restrict__ statsG, __bf16* __restrict__ vout, int use_v16)
{
  __shared__ __align__(16) char lds[A_BYTES + 3 * B_BYTES + 2048];   // 151552 B
  const int bb   = blockIdx.x >> 4;
  const int ho0  = (blockIdx.x & 15) << 2;   // 4 output rows per block
  const int tid  = threadIdx.x;
  const int lane = tid & 63;
  const int wid  = tid >> 6;                 // 16 waves: 4 (m) x 4 (co)
  const int wr   = wid >> 2;                 // image row ho0+wr
  const int wc   = wid & 3;                  // co quarter (64)
  const int l15  = lane & 15;

  f32x4 acc[4][4];
#pragma unroll
  for (int i = 0; i < 4; ++i)
#pragma unroll
    for (int j = 0; j < 4; ++j)
#pragma unroll
      for (int r = 0; r < 4; ++r) acc[i][j][r] = 0.f;

  const char* zb = (const char*)zerob;

  // hoisted B ds_read byte offsets (constant across phases)
  int boff[4][2];
#pragma unroll
  for (int j = 0; j < 4; ++j)
#pragma unroll
    for (int kk = 0; kk < 2; ++kk) {
      const int co     = (wc << 6) + (j << 4) + l15;
      const int ci_off = (kk << 5) + ((lane >> 4) << 3);
      boff[j][kk] = ((co << 7) + (ci_off << 1)) ^ ((co & 7) << 4);
    }
  // B stage per-lane source offset within a contiguous 32KB Wt phase-tile
  const int bl = lane >> 3;
  const int bsrcLane = (bl << 7) + (((lane & 7) ^ (bl & 7)) << 4);

  // ---- stage A slab for ci-block s: slab[r=6][c=66][ci=64] bf16, 128B/pos.
  auto stageA = [&](int s) {
    const int ci0 = s << 6;
    for (int t = wid; t < 50; t += 16) {
      const int ch = (t << 3) + (lane >> 3);   // pos = r*66+c, 0..399
      const int r  = ch / 66;
      const int c  = ch - r * 66;
      const int ir = ho0 - 1 + r;              // image row
      const int ic = c - 1;                    // image col
      const int k  = (lane & 7) ^ (ch & 7);    // logical 16B slot (8 ci elems)
      const char* src;
      if (ch < 396 && ir >= 0 && ir < 64 && ic >= 0 && ic < 64)
        src = (const char*)(xT + ((((size_t)bb << 6) + ir) * 64 + ic) * 256 + ci0 + (k << 3));
      else
        src = zb + (k << 4);
      gload_lds16(src, lds + (t << 10));
    }
  };

  // ---- stage B tile (2 loads per wave) for flat phase ph into buffer bi.
  auto stageB = [&](int ph, int bi) {
    char* buf = lds + A_BYTES + bi * B_BYTES;
    const int s2 = ph / 9, tp = ph - s2 * 9;
    const char* wsrc = (const char*)Wt + ((size_t)(tp * 4 + s2) << 15) + bsrcLane;
    gload_lds16(wsrc + (wid << 10), buf + (wid << 10));
    gload_lds16(wsrc + ((wid + 16) << 10), buf + ((wid + 16) << 10));
  };

  // prologue: A(0), B(0), B(1) staged and drained
  stageA(0);
  stageB(0, 0);
  stageB(1, 1);
  asm volatile("s_waitcnt vmcnt(0)" ::: "memory");
  __builtin_amdgcn_s_barrier();
  asm volatile("" ::: "memory");

  int s = 0, tap = 0, bcur = 0;
  for (int p = 0; p < 36; ++p) {
    if (p + 2 < 36) {
      int bnx = bcur + 2; if (bnx >= 3) bnx -= 3;
      stageB(p + 2, bnx);                      // issue BEFORE compute (T3)
    }
    const int dh = (tap >= 6) ? 2 : (tap >= 3 ? 1 : 0);
    const int dw = tap - dh * 3;
    const char* Bb = lds + A_BYTES + bcur * B_BYTES;
    __builtin_amdgcn_s_setprio(1);
#pragma unroll
    for (int kk = 0; kk < 2; ++kk) {
      const int ci_off = (kk << 5) + ((lane >> 4) << 3);
      bf16x8 av[4];
#pragma unroll
      for (int i = 0; i < 4; ++i) {
        const int pos = (wr + dh) * 66 + (i << 4) + l15 + dw;
        const int off = ((pos << 7) + (ci_off << 1)) ^ ((pos & 7) << 4);
        av[i] = *(const bf16x8*)(lds + off);
      }
#pragma unroll
      for (int j = 0; j < 4; ++j) {
        const bf16x8 bv = *(const bf16x8*)(Bb + boff[j][kk]);
#pragma unroll
        for (int i = 0; i < 4; ++i)
          acc[i][j] = __builtin_amdgcn_mfma_f32_16x16x32_bf16(av[i], bv, acc[i][j], 0, 0, 0);
      }
    }
    __builtin_amdgcn_s_setprio(0);

    if (tap == 8 && s < 3) {
      asm volatile("s_waitcnt vmcnt(0)" ::: "memory");
      __builtin_amdgcn_s_barrier();
      asm volatile("" ::: "memory");
      stageA(s + 1);
      asm volatile("s_waitcnt vmcnt(0)" ::: "memory");
      __builtin_amdgcn_s_barrier();
      asm volatile("" ::: "memory");
    } else if (p + 2 < 36) {
      asm volatile("s_waitcnt vmcnt(2)" ::: "memory");
      __builtin_amdgcn_s_barrier();
      asm volatile("" ::: "memory");
    } else if (p < 35) {
      asm volatile("s_waitcnt vmcnt(0)" ::: "memory");
      __builtin_amdgcn_s_barrier();
      asm volatile("" ::: "memory");
    }
    if (++tap == 9) { tap = 0; ++s; }
    if (++bcur == 3) bcur = 0;
  }

  // ---- epilogue: v = x+conv+beff (fragment layout), stats in-reg (f32),
  // v stored bf16 (use_v16) or f32 (fallback)
  __syncthreads();
  float* lstat = (float*)(lds + A_BYTES + 3 * B_BYTES);   // 512 floats
  if (tid < 512) lstat[tid] = 0.f;
  __syncthreads();

  const int wq = lane >> 4;                    // 0..3 (w quad group)
  const int ho = ho0 + wr;
#pragma unroll
  for (int j = 0; j < 4; ++j) {
    const int co = (wc << 6) + (j << 4) + l15;
    const float be = beff[co];
    const size_t base = ((((size_t)bb << 8) + (size_t)co) << 12) + (ho << 6);
    float r1 = 0.f, r2 = 0.f;
#pragma unroll
    for (int i = 0; i < 4; ++i) {
      const int w0 = (i << 4) + (wq << 2);
      const float4 xv = *(const float4*)(x + base + w0);
      float4 v;
      v.x = acc[i][j][0] + xv.x + be;
      v.y = acc[i][j][1] + xv.y + be;
      v.z = acc[i][j][2] + xv.z + be;
      v.w = acc[i][j][3] + xv.w + be;
      r1 += v.x + v.y + v.z + v.w;
      r2 += v.x * v.x + v.y * v.y + v.z * v.z + v.w * v.w;
      if (use_v16) {
        union { __bf16 h[4]; uint2 u2; } pk;
        pk.h[0] = (__bf16)v.x; pk.h[1] = (__bf16)v.y;
        pk.h[2] = (__bf16)v.z; pk.h[3] = (__bf16)v.w;
        *(uint2*)(vout + base + w0) = pk.u2;
      } else {
        *(float4*)(out + base + w0) = v;
      }
    }
    r1 += __shfl_xor(r1, 16); r2 += __shfl_xor(r2, 16);
    r1 += __shfl_xor(r1, 32); r2 += __shfl_xor(r2, 32);
    if (lane < 16) {
      atomicAdd(&lstat[co], r1);
      atomicAdd(&lstat[256 + co], r2);
    }
  }
  __syncthreads();
  if (tid < 512) atomicAdd(&statsG[tid], lstat[tid]);
}

// K3a: BN finalize + apply from bf16 v -> f32 out (grid-stride, 2048 blocks)
__global__ void k_apply_v16(const __bf16* __restrict__ v, float* __restrict__ out,
                            const float* __restrict__ statsG,
                            const float* __restrict__ gamma,
                            const float* __restrict__ beta) {
  __shared__ float ssc[256], ssh[256];
  const int t = threadIdx.x;    // 256
  {
    const float mean = statsG[t] * (1.f / 65536.f);
    const float var  = statsG[256 + t] * (1.f / 65536.f) - mean * mean;
    const float inv  = rsqrtf(var + 1e-5f);
    const float sc   = gamma[t] * inv;
    ssc[t] = sc;
    ssh[t] = beta[t] - mean * sc;
  }
  __syncthreads();
  const ushort4* vp = (const ushort4*)v;
  float4* op = (float4*)out;
  for (size_t g = (size_t)blockIdx.x * 256 + t; g < 4194304ul; g += (size_t)gridDim.x * 256) {
    const int co = (int)((g >> 10) & 255);
    const ushort4 pv = vp[g];
    const float sc = ssc[co], sh = ssh[co];
    float4 y;
    y.x = __uint_as_float((uint32_t)pv.x << 16) * sc + sh;
    y.y = __uint_as_float((uint32_t)pv.y << 16) * sc + sh;
    y.z = __uint_as_float((uint32_t)pv.z << 16) * sc + sh;
    y.w = __uint_as_float((uint32_t)pv.w << 16) * sc + sh;
    op[g] = y;
  }
}

// K3b: fallback — BN finalize + in-place apply on f32 out
__global__ void k_apply_f32(float* __restrict__ out, const float* __restrict__ statsG,
                            const float* __restrict__ gamma,
                            const float* __restrict__ beta) {
  __shared__ float ssc[256], ssh[256];
  const int t = threadIdx.x;    // 256
  {
    const float mean = statsG[t] * (1.f / 65536.f);
    const float var  = statsG[256 + t] * (1.f / 65536.f) - mean * mean;
    const float inv  = rsqrtf(var + 1e-5f);
    const float sc   = gamma[t] * inv;
    ssc[t] = sc;
    ssh[t] = beta[t] - mean * sc;
  }
  __syncthreads();
  float4* op = (float4*)out;
  for (size_t g = (size_t)blockIdx.x * 256 + t; g < 4194304ul; g += (size_t)gridDim.x * 256) {
    const int co = (int)((g >> 10) & 255);
    float4 y = op[g];
    const float sc = ssc[co], sh = ssh[co];
    y.x = y.x * sc + sh; y.y = y.y * sc + sh;
    y.z = y.z * sc + sh; y.w = y.w * sc + sh;
    op[g] = y;
  }
}

extern "C" void kernel_launch(void* const* d_in, const int* in_sizes, int n_in,
                              void* d_out, int out_size, void* d_ws, size_t ws_size,
                              hipStream_t stream) {
  const float* x     = (const float*)d_in[0];
  const float* wall  = (const float*)d_in[1];
  const float* bias  = (const float*)d_in[2];
  const float* alpha = (const float*)d_in[3];
  const float* gamma = (const float*)d_in[4];
  const float* beta  = (const float*)d_in[5];
  float* out = (float*)d_out;

  char* ws = (char*)d_ws;
  __bf16* xT     = (__bf16*)(ws + XT_OFF);
  __bf16* Wt     = (__bf16*)(ws + WT_OFF);
  float*  beff   = (float*)(ws + BEFF_OFF);
  float*  zerob  = (float*)(ws + ZERO_OFF);
  float*  statsG = (float*)(ws + STATS_OFF);
  __bf16* vbuf   = (__bf16*)(ws + V_OFF);
  const int use_v16 = (ws_size >= WS_NEED) ? 1 : 0;

  k_wred<<<256, 256, 0, stream>>>(wall, bias, alpha, Wt, beff, zerob, statsG);
  k_xpose<<<1024, 256, 0, stream>>>(x, xT);
  k_conv<<<256, 1024, 0, stream>>>(x, xT, Wt, beff, (const __bf16*)zerob, out,
                                   statsG, vbuf, use_v16);
  if (use_v16)
    k_apply_v16<<<2048, 256, 0, stream>>>(vbuf, out, statsG, gamma, beta);
  else
    k_apply_f32<<<2048, 256, 0, stream>>>(out, statsG, gamma, beta);
}

// Round 13
// 122.723 us; speedup vs baseline: 1.3924x; 1.0323x over previous
//
#include <hip/hip_runtime.h>
#include <stdint.h>

typedef __attribute__((__ext_vector_type__(8))) __bf16 bf16x8;
typedef __attribute__((__ext_vector_type__(4))) float  f32x4;

// ---- workspace layout (bytes) ----
#define XT_OFF    0ul          // 16*64*64*256 bf16 = 33,554,432
#define WT_OFF    33554432ul   // 36*16384 bf16     =  1,179,648  [tap][s][co][ci64]
#define BEFF_OFF  34734080ul   // 256 f32
#define ZERO_OFF  34737152ul   // 256 B zeros
#define STATS_OFF 34737408ul   // 512 f32 (sum, sumsq per channel)
#define V_OFF     35651584ul   // 16M bf16 = 33,554,432 (v intermediate, NCHW)
#define WS_NEED   (V_OFF + 33554432ul)

__device__ inline void gload_lds16(const void* g, void* l) {
  __builtin_amdgcn_global_load_lds((const __attribute__((address_space(1))) void*)g,
                                   (__attribute__((address_space(3))) void*)l,
                                   16, 0, 0);
}

// K1 (merged): blocks 0..255 = weight reduction; 256..1279 = x transpose.
// Merging lets the two independent passes overlap on the CUs.
__global__ void k_prep(const float* __restrict__ w, const float* __restrict__ bias,
                       const float* __restrict__ alpha_p, __bf16* __restrict__ Wt,
                       float* __restrict__ beff, float* __restrict__ zerob,
                       float* __restrict__ statsG,
                       const float* __restrict__ x, __bf16* __restrict__ xT) {
  __shared__ __bf16 lds[64 * 258];
  if (blockIdx.x < 256) {
    const int co = blockIdx.x;
    const int ci = threadIdx.x;   // 256
    float a[9];
#pragma unroll
    for (int t = 0; t < 9; ++t) a[t] = 0.f;
#pragma unroll
    for (int r = 0; r < 2; ++r)
#pragma unroll
      for (int o = 0; o < 8; ++o) {
        const float* p = w + ((size_t)(r * 256 + co) * 2048 + (size_t)(o * 256 + ci)) * 9;
#pragma unroll
        for (int t = 0; t < 9; ++t) a[t] += p[t];
      }
    const float sc = alpha_p[0] * 0.0625f;      // alpha / (NORI*NROT)
    const int s = ci >> 6, cis = ci & 63;
#pragma unroll
    for (int t = 0; t < 9; ++t)
      Wt[(size_t)(t * 4 + s) * 16384 + co * 64 + cis] = (__bf16)(a[t] * sc);
    if (ci == 0) beff[co] = (bias[co] + bias[256 + co]) * 8.0f * sc;
    if (blockIdx.x == 0) {
      statsG[ci] = 0.f; statsG[256 + ci] = 0.f;
      if (ci < 64) zerob[ci] = 0.f;
    }
  } else {
    // ---- x[b][ci][h][w] f32 -> xT[b][h][w][ci] bf16 (LDS-tiled transpose)
    int bh = blockIdx.x - 256;    // 16*64
    int b = bh >> 6, h = bh & 63;
    int t = threadIdx.x;          // 256
    int w2 = t & 63, cg = t >> 6;
    const float* xb = x + ((size_t)b * 16384 + h) * 64;   // + ci*4096 + w
#pragma unroll 4
    for (int cb = 0; cb < 256; cb += 4) {
      int ci = cb + cg;
      lds[w2 * 258 + ci] = (__bf16)xb[(size_t)ci * 4096 + w2];
    }
    __syncthreads();
    const uint32_t* l32 = (const uint32_t*)lds;
    uint32_t* o32 = (uint32_t*)(xT + ((size_t)b * 64 + h) * 64 * 256);
    int c2 = t & 127, wg = t >> 7;              // 2 w per iter
    for (int w0 = 0; w0 < 64; w0 += 2) {
      int ww = w0 + wg;
      o32[ww * 128 + c2] = l32[ww * 129 + c2];
    }
  }
}

// K2: implicit-GEMM conv + residual + fused BN stats (R11 main loop, unchanged).
// 256 blocks (1/CU), 1024 threads = 16 waves (4m x 4n), wave tile 64x64, 4 w/SIMD.
// Epilogue: v = x+conv+beff; stats in-register (f32, unrounded); v repacked
// per-wave through LDS (intra-wave, no barriers) and stored as bf16 FULL
// 64B lines into vbuf (NCHW layout) — avoids R12's partial-line write-allocate.
#define A_BYTES 51200            // 50 chunks * 1024 (396 pos * 128B, padded)
#define B_BYTES 32768

__global__ __launch_bounds__(1024) void k_conv(
    const float* __restrict__ x, const __bf16* __restrict__ xT,
    const __bf16* __restrict__ Wt, const float* __restrict__ beff,
    const __bf16* __restrict__ zerob, float* __restrict__ out,
    float* __restrict__ statsG, __bf16* __restrict__ vout, int use_v16)
{
  __shared__ __align__(16) char lds[A_BYTES + 3 * B_BYTES + 2048];   // 151552 B
  const int bb   = blockIdx.x >> 4;
  const int ho0  = (blockIdx.x & 15) << 2;   // 4 output rows per block
  const int tid  = threadIdx.x;
  const int lane = tid & 63;
  const int wid  = tid >> 6;                 // 16 waves: 4 (m) x 4 (co)
  const int wr   = wid >> 2;                 // image row ho0+wr
  const int wc   = wid & 3;                  // co quarter (64)
  const int l15  = lane & 15;

  f32x4 acc[4][4];
#pragma unroll
  for (int i = 0; i < 4; ++i)
#pragma unroll
    for (int j = 0; j < 4; ++j)
#pragma unroll
      for (int r = 0; r < 4; ++r) acc[i][j][r] = 0.f;

  const char* zb = (const char*)zerob;

  // hoisted B ds_read byte offsets (constant across phases)
  int boff[4][2];
#pragma unroll
  for (int j = 0; j < 4; ++j)
#pragma unroll
    for (int kk = 0; kk < 2; ++kk) {
      const int co     = (wc << 6) + (j << 4) + l15;
      const int ci_off = (kk << 5) + ((lane >> 4) << 3);
      boff[j][kk] = ((co << 7) + (ci_off << 1)) ^ ((co & 7) << 4);
    }
  // B stage per-lane source offset within a contiguous 32KB Wt phase-tile
  const int bl = lane >> 3;
  const int bsrcLane = (bl << 7) + (((lane & 7) ^ (bl & 7)) << 4);

  // ---- stage A slab for ci-block s: slab[r=6][c=66][ci=64] bf16, 128B/pos.
  // 16B-slot swizzle: phys_slot = logical_slot ^ (pos&7); linear LDS dest +
  // inverse-swizzled global source (G21).
  auto stageA = [&](int s) {
    const int ci0 = s << 6;
    for (int t = wid; t < 50; t += 16) {
      const int ch = (t << 3) + (lane >> 3);   // pos = r*66+c, 0..399
      const int r  = ch / 66;
      const int c  = ch - r * 66;
      const int ir = ho0 - 1 + r;              // image row
      const int ic = c - 1;                    // image col
      const int k  = (lane & 7) ^ (ch & 7);    // logical 16B slot (8 ci elems)
      const char* src;
      if (ch < 396 && ir >= 0 && ir < 64 && ic >= 0 && ic < 64)
        src = (const char*)(xT + ((((size_t)bb << 6) + ir) * 64 + ic) * 256 + ci0 + (k << 3));
      else
        src = zb + (k << 4);
      gload_lds16(src, lds + (t << 10));
    }
  };

  // ---- stage B tile (2 loads per wave) for flat phase ph into buffer bi.
  auto stageB = [&](int ph, int bi) {
    char* buf = lds + A_BYTES + bi * B_BYTES;
    const int s2 = ph / 9, tp = ph - s2 * 9;
    const char* wsrc = (const char*)Wt + ((size_t)(tp * 4 + s2) << 15) + bsrcLane;
    gload_lds16(wsrc + (wid << 10), buf + (wid << 10));
    gload_lds16(wsrc + ((wid + 16) << 10), buf + ((wid + 16) << 10));
  };

  // prologue: A(0), B(0), B(1) staged and drained
  stageA(0);
  stageB(0, 0);
  stageB(1, 1);
  asm volatile("s_waitcnt vmcnt(0)" ::: "memory");
  __builtin_amdgcn_s_barrier();
  asm volatile("" ::: "memory");

  int s = 0, tap = 0, bcur = 0;
  for (int p = 0; p < 36; ++p) {
    if (p + 2 < 36) {
      int bnx = bcur + 2; if (bnx >= 3) bnx -= 3;
      stageB(p + 2, bnx);                      // issue BEFORE compute (T3)
    }
    const int dh = (tap >= 6) ? 2 : (tap >= 3 ? 1 : 0);
    const int dw = tap - dh * 3;
    const char* Bb = lds + A_BYTES + bcur * B_BYTES;
    __builtin_amdgcn_s_setprio(1);
#pragma unroll
    for (int kk = 0; kk < 2; ++kk) {
      const int ci_off = (kk << 5) + ((lane >> 4) << 3);
      bf16x8 av[4];
#pragma unroll
      for (int i = 0; i < 4; ++i) {
        const int pos = (wr + dh) * 66 + (i << 4) + l15 + dw;
        const int off = ((pos << 7) + (ci_off << 1)) ^ ((pos & 7) << 4);
        av[i] = *(const bf16x8*)(lds + off);
      }
#pragma unroll
      for (int j = 0; j < 4; ++j) {
        const bf16x8 bv = *(const bf16x8*)(Bb + boff[j][kk]);
#pragma unroll
        for (int i = 0; i < 4; ++i)
          acc[i][j] = __builtin_amdgcn_mfma_f32_16x16x32_bf16(av[i], bv, acc[i][j], 0, 0, 0);
      }
    }
    __builtin_amdgcn_s_setprio(0);

    if (tap == 8 && s < 3) {
      asm volatile("s_waitcnt vmcnt(0)" ::: "memory");
      __builtin_amdgcn_s_barrier();
      asm volatile("" ::: "memory");
      stageA(s + 1);
      asm volatile("s_waitcnt vmcnt(0)" ::: "memory");
      __builtin_amdgcn_s_barrier();
      asm volatile("" ::: "memory");
    } else if (p + 2 < 36) {
      asm volatile("s_waitcnt vmcnt(2)" ::: "memory");
      __builtin_amdgcn_s_barrier();
      asm volatile("" ::: "memory");
    } else if (p < 35) {
      asm volatile("s_waitcnt vmcnt(0)" ::: "memory");
      __builtin_amdgcn_s_barrier();
      asm volatile("" ::: "memory");
    }
    if (++tap == 9) { tap = 0; ++s; }
    if (++bcur == 3) bcur = 0;
  }

  // ---- epilogue: v = x+conv+beff, stats in-reg (f32), bf16 v via per-wave
  // LDS repack -> full-line 16B/lane stores (use_v16), else f32 to out.
  __syncthreads();
  float* lstat = (float*)(lds + 32768);        // 512 floats (after repack area)
  if (tid < 512) lstat[tid] = 0.f;
  __syncthreads();

  char* wreg = lds + wid * 2048;               // this wave's repack region
  const int wq = lane >> 4;                    // 0..3 (w quad group)
  const int ho = ho0 + wr;
  const int xorco = (l15 & 7) << 4;
#pragma unroll
  for (int j = 0; j < 4; ++j) {
    const int co = (wc << 6) + (j << 4) + l15;
    const float be = beff[co];
    const size_t base = ((((size_t)bb << 8) + (size_t)co) << 12) + (ho << 6);
    float r1 = 0.f, r2 = 0.f;
#pragma unroll
    for (int i = 0; i < 4; ++i) {
      const int w0 = (i << 4) + (wq << 2);
      const float4 xv = *(const float4*)(x + base + w0);
      float4 v;
      v.x = acc[i][j][0] + xv.x + be;
      v.y = acc[i][j][1] + xv.y + be;
      v.z = acc[i][j][2] + xv.z + be;
      v.w = acc[i][j][3] + xv.w + be;
      r1 += v.x + v.y + v.z + v.w;
      r2 += v.x * v.x + v.y * v.y + v.z * v.z + v.w * v.w;
      if (use_v16) {
        union { __bf16 h[4]; uint64_t u; } pk;
        pk.h[0] = (__bf16)v.x; pk.h[1] = (__bf16)v.y;
        pk.h[2] = (__bf16)v.z; pk.h[3] = (__bf16)v.w;
        // logical [co=l15][w] bf16: addr = l15*128 + w*2, w = i*16+wq*4
        const int wa = (l15 << 7) + (i << 5) + (wq << 3);
        *(uint64_t*)(wreg + (wa ^ xorco)) = pk.u;
      } else {
        *(float4*)(out + base + w0) = v;
      }
    }
    r1 += __shfl_xor(r1, 16); r2 += __shfl_xor(r2, 16);
    r1 += __shfl_xor(r1, 32); r2 += __shfl_xor(r2, 32);
    if (lane < 16) {
      atomicAdd(&lstat[co], r1);
      atomicAdd(&lstat[256 + co], r2);
    }
    if (use_v16) {
      asm volatile("s_waitcnt lgkmcnt(0)" ::: "memory");   // wave's writes visible
#pragma unroll
      for (int t2 = 0; t2 < 2; ++t2) {
        const int co_r = lane >> 2;              // 0..15
        const int ch   = (lane & 3) + (t2 << 2); // 16B chunk = 8 w
        const int ra   = (co_r << 7) + (ch << 4);
        const uint4 pv = *(const uint4*)(wreg + (ra ^ ((co_r & 7) << 4)));
        const int co_g = (wc << 6) + (j << 4) + co_r;
        const size_t oi = ((((size_t)bb << 8) + (size_t)co_g) << 12) + (ho << 6) + (ch << 3);
        *(uint4*)(vout + oi) = pv;               // 16B, 4 lanes/co -> 64B lines
      }
      asm volatile("s_waitcnt lgkmcnt(0)" ::: "memory");   // reads done before next j
    }
  }
  __syncthreads();
  if (tid < 512) atomicAdd(&statsG[tid], lstat[tid]);
}

// K3a: BN finalize + apply from bf16 v (NCHW) -> f32 out (grid-stride)
__global__ void k_apply_v16(const __bf16* __restrict__ v, float* __restrict__ out,
                            const float* __restrict__ statsG,
                            const float* __restrict__ gamma,
                            const float* __restrict__ beta) {
  __shared__ float ssc[256], ssh[256];
  const int t = threadIdx.x;    // 256
  {
    const float mean = statsG[t] * (1.f / 65536.f);
    const float var  = statsG[256 + t] * (1.f / 65536.f) - mean * mean;
    const float inv  = rsqrtf(var + 1e-5f);
    const float sc   = gamma[t] * inv;
    ssc[t] = sc;
    ssh[t] = beta[t] - mean * sc;
  }
  __syncthreads();
  const uint4* vp = (const uint4*)v;           // 8 bf16 per uint4
  for (size_t g = (size_t)blockIdx.x * 256 + t; g < 2097152ul; g += (size_t)gridDim.x * 256) {
    const int co = (int)((g >> 9) & 255);      // 512 chunks of 8 per (b,co) plane
    const uint4 pv = vp[g];
    const float sc = ssc[co], sh = ssh[co];
    float4 y0, y1;
    y0.x = __uint_as_float((pv.x & 0xffffu) << 16) * sc + sh;
    y0.y = __uint_as_float(pv.x & 0xffff0000u) * sc + sh;
    y0.z = __uint_as_float((pv.y & 0xffffu) << 16) * sc + sh;
    y0.w = __uint_as_float(pv.y & 0xffff0000u) * sc + sh;
    y1.x = __uint_as_float((pv.z & 0xffffu) << 16) * sc + sh;
    y1.y = __uint_as_float(pv.z & 0xffff0000u) * sc + sh;
    y1.z = __uint_as_float((pv.w & 0xffffu) << 16) * sc + sh;
    y1.w = __uint_as_float(pv.w & 0xffff0000u) * sc + sh;
    float4* op = (float4*)(out + g * 8);
    op[0] = y0;
    op[1] = y1;
  }
}

// K3b: fallback — BN finalize + in-place apply on f32 out
__global__ void k_apply_f32(float* __restrict__ out, const float* __restrict__ statsG,
                            const float* __restrict__ gamma,
                            const float* __restrict__ beta) {
  __shared__ float ssc[256], ssh[256];
  const int t = threadIdx.x;    // 256
  {
    const float mean = statsG[t] * (1.f / 65536.f);
    const float var  = statsG[256 + t] * (1.f / 65536.f) - mean * mean;
    const float inv  = rsqrtf(var + 1e-5f);
    const float sc   = gamma[t] * inv;
    ssc[t] = sc;
    ssh[t] = beta[t] - mean * sc;
  }
  __syncthreads();
  float4* op = (float4*)out;
  for (size_t g = (size_t)blockIdx.x * 256 + t; g < 4194304ul; g += (size_t)gridDim.x * 256) {
    const int co = (int)((g >> 10) & 255);
    float4 y = op[g];
    const float sc = ssc[co], sh = ssh[co];
    y.x = y.x * sc + sh; y.y = y.y * sc + sh;
    y.z = y.z * sc + sh; y.w = y.w * sc + sh;
    op[g] = y;
  }
}

extern "C" void kernel_launch(void* const* d_in, const int* in_sizes, int n_in,
                              void* d_out, int out_size, void* d_ws, size_t ws_size,
                              hipStream_t stream) {
  const float* x     = (const float*)d_in[0];
  const float* wall  = (const float*)d_in[1];
  const float* bias  = (const float*)d_in[2];
  const float* alpha = (const float*)d_in[3];
  const float* gamma = (const float*)d_in[4];
  const float* beta  = (const float*)d_in[5];
  float* out = (float*)d_out;

  char* ws = (char*)d_ws;
  __bf16* xT     = (__bf16*)(ws + XT_OFF);
  __bf16* Wt     = (__bf16*)(ws + WT_OFF);
  float*  beff   = (float*)(ws + BEFF_OFF);
  float*  zerob  = (float*)(ws + ZERO_OFF);
  float*  statsG = (float*)(ws + STATS_OFF);
  __bf16* vbuf   = (__bf16*)(ws + V_OFF);
  const int use_v16 = (ws_size >= WS_NEED) ? 1 : 0;

  k_prep<<<1280, 256, 0, stream>>>(wall, bias, alpha, Wt, beff, zerob, statsG, x, xT);
  k_conv<<<256, 1024, 0, stream>>>(x, xT, Wt, beff, (const __bf16*)zerob, out,
                                   statsG, vbuf, use_v16);
  if (use_v16)
    k_apply_v16<<<2048, 256, 0, stream>>>(vbuf, out, statsG, gamma, beta);
  else
    k_apply_f32<<<2048, 256, 0, stream>>>(out, statsG, gamma, beta);
}

// Round 14
// 115.008 us; speedup vs baseline: 1.4858x; 1.0671x over previous
//
#include <hip/hip_runtime.h>
#include <stdint.h>

typedef __attribute__((__ext_vector_type__(8))) __bf16 bf16x8;
typedef __attribute__((__ext_vector_type__(4))) float  f32x4;

// ---- workspace layout (bytes) ----
#define XT_OFF    0ul          // 16*64*64*256 bf16 = 33,554,432
#define WT_OFF    33554432ul   // 36*16384 bf16     =  1,179,648  [tap][s][co][ci64]
#define BEFF_OFF  34734080ul   // 256 f32
#define ZERO_OFF  34737152ul   // 256 B zeros
#define STATS_OFF 34737408ul   // 512 f32 (sum, sumsq per channel)
#define V_OFF     35651584ul   // 16M bf16 = 33,554,432 (v intermediate, NCHW)
#define WS_NEED   (V_OFF + 33554432ul)

__device__ inline void gload_lds16(const void* g, void* l) {
  __builtin_amdgcn_global_load_lds((const __attribute__((address_space(1))) void*)g,
                                   (__attribute__((address_space(3))) void*)l,
                                   16, 0, 0);
}

// K1 (merged): blocks 0..255 = weight reduction; 256..1279 = x transpose.
__global__ void k_prep(const float* __restrict__ w, const float* __restrict__ bias,
                       const float* __restrict__ alpha_p, __bf16* __restrict__ Wt,
                       float* __restrict__ beff, float* __restrict__ zerob,
                       float* __restrict__ statsG,
                       const float* __restrict__ x, __bf16* __restrict__ xT) {
  __shared__ __bf16 lds[64 * 258];
  if (blockIdx.x < 256) {
    const int co = blockIdx.x;
    const int ci = threadIdx.x;   // 256
    float a[9];
#pragma unroll
    for (int t = 0; t < 9; ++t) a[t] = 0.f;
#pragma unroll
    for (int r = 0; r < 2; ++r)
#pragma unroll
      for (int o = 0; o < 8; ++o) {
        const float* p = w + ((size_t)(r * 256 + co) * 2048 + (size_t)(o * 256 + ci)) * 9;
#pragma unroll
        for (int t = 0; t < 9; ++t) a[t] += p[t];
      }
    const float sc = alpha_p[0] * 0.0625f;      // alpha / (NORI*NROT)
    const int s = ci >> 6, cis = ci & 63;
#pragma unroll
    for (int t = 0; t < 9; ++t)
      Wt[(size_t)(t * 4 + s) * 16384 + co * 64 + cis] = (__bf16)(a[t] * sc);
    if (ci == 0) beff[co] = (bias[co] + bias[256 + co]) * 8.0f * sc;
    if (blockIdx.x == 0) {
      statsG[ci] = 0.f; statsG[256 + ci] = 0.f;
      if (ci < 64) zerob[ci] = 0.f;
    }
  } else {
    // ---- x[b][ci][h][w] f32 -> xT[b][h][w][ci] bf16 (LDS-tiled transpose)
    int bh = blockIdx.x - 256;    // 16*64
    int b = bh >> 6, h = bh & 63;
    int t = threadIdx.x;          // 256
    int w2 = t & 63, cg = t >> 6;
    const float* xb = x + ((size_t)b * 16384 + h) * 64;   // + ci*4096 + w
#pragma unroll 4
    for (int cb = 0; cb < 256; cb += 4) {
      int ci = cb + cg;
      lds[w2 * 258 + ci] = (__bf16)xb[(size_t)ci * 4096 + w2];
    }
    __syncthreads();
    const uint32_t* l32 = (const uint32_t*)lds;
    uint32_t* o32 = (uint32_t*)(xT + ((size_t)b * 64 + h) * 64 * 256);
    int c2 = t & 127, wg = t >> 7;              // 2 w per iter
    for (int w0 = 0; w0 < 64; w0 += 2) {
      int ww = w0 + wg;
      o32[ww * 128 + c2] = l32[ww * 129 + c2];
    }
  }
}

// K2: implicit-GEMM conv + residual + fused BN stats.
// R14: TWO blocks per CU (decoupled barrier domains -> cross-block overlap of
// stage/drain with MFMA). 512 blocks of 512 thr (8 waves = 4m x 2n), block
// tile M=256 (4 rows x 64 w) x N=128 (co half). Wave tile 64x64 (unchanged
// per-wave LDS reuse). LDS = A 51200 + B 16384 + lstat = 68.6 KB -> 2/CU.
// Per phase: [stageA if s-bound] stageB(p) -> vmcnt(0) -> bar -> MFMA -> bar.
// blockIdx encoding pairs co-halves on the same XCD slot: ch = (u>>3)&1.
#define A_BYTES 51200            // 50 chunks * 1024 (396 pos * 128B, padded)
#define B_BYTES 16384            // 128 co x 64 ci bf16

__global__ __launch_bounds__(512, 4) void k_conv(
    const float* __restrict__ x, const __bf16* __restrict__ xT,
    const __bf16* __restrict__ Wt, const float* __restrict__ beff,
    const __bf16* __restrict__ zerob, float* __restrict__ out,
    float* __restrict__ statsG, __bf16* __restrict__ vout, int use_v16)
{
  __shared__ __align__(16) char lds[A_BYTES + B_BYTES + 1024];   // 68608 B
  const int u    = blockIdx.x;               // 512 blocks
  const int ch   = (u >> 3) & 1;             // co half (pairs share XCD slot u&7)
  const int pairid = (u & 7) | ((u >> 4) << 3);   // 0..255
  const int bb   = pairid >> 4;              // batch
  const int ho0  = (pairid & 15) << 2;       // 4 output rows per block
  const int tid  = threadIdx.x;
  const int lane = tid & 63;
  const int wid  = tid >> 6;                 // 8 waves: 4 (m rows) x 2 (co 64s)
  const int wr   = wid >> 1;                 // image row ho0+wr
  const int wc   = wid & 1;                  // co quarter-of-half (64)
  const int l15  = lane & 15;

  f32x4 acc[4][4];
#pragma unroll
  for (int i = 0; i < 4; ++i)
#pragma unroll
    for (int j = 0; j < 4; ++j)
#pragma unroll
      for (int r = 0; r < 4; ++r) acc[i][j][r] = 0.f;

  const char* zb = (const char*)zerob;

  // hoisted B ds_read byte offsets within the 16KB tile (co_local 0..127)
  int boff[4][2];
#pragma unroll
  for (int j = 0; j < 4; ++j)
#pragma unroll
    for (int kk = 0; kk < 2; ++kk) {
      const int col    = (wc << 6) + (j << 4) + l15;      // 0..127
      const int ci_off = (kk << 5) + ((lane >> 4) << 3);
      boff[j][kk] = ((col << 7) + (ci_off << 1)) ^ ((col & 7) << 4);
    }
  // B stage per-lane source offset within the 16KB half-tile
  const int bl = lane >> 3;
  const int bsrcLane = (bl << 7) + (((lane & 7) ^ (bl & 7)) << 4);

  // ---- stage A slab for ci-block s: slab[r=6][c=66][ci=64] bf16, 128B/pos.
  // 16B-slot swizzle: phys = logical ^ (pos&7); linear dest + inverse-swz src.
  auto stageA = [&](int s) {
    const int ci0 = s << 6;
    for (int t = wid; t < 50; t += 8) {
      const int chk = (t << 3) + (lane >> 3);  // pos = r*66+c, 0..399
      const int r  = chk / 66;
      const int c  = chk - r * 66;
      const int ir = ho0 - 1 + r;              // image row
      const int ic = c - 1;                    // image col
      const int k  = (lane & 7) ^ (chk & 7);   // logical 16B slot (8 ci elems)
      const char* src;
      if (chk < 396 && ir >= 0 && ir < 64 && ic >= 0 && ic < 64)
        src = (const char*)(xT + ((((size_t)bb << 6) + ir) * 64 + ic) * 256 + ci0 + (k << 3));
      else
        src = zb + (k << 4);
      gload_lds16(src, lds + (t << 10));
    }
  };

  // ---- stage B half-tile for flat phase ph (2 loads per wave, 16 chunks)
  auto stageB = [&](int ph) {
    char* buf = lds + A_BYTES;
    const int s2 = ph / 9, tp = ph - s2 * 9;
    const char* wsrc = (const char*)Wt + ((size_t)(tp * 4 + s2) << 15) + (ch << 14) + bsrcLane;
    gload_lds16(wsrc + (wid << 10), buf + (wid << 10));
    gload_lds16(wsrc + ((wid + 8) << 10), buf + ((wid + 8) << 10));
  };

  int s = 0, tap = 0;
  for (int p = 0; p < 36; ++p) {
    if (tap == 0) stageA(s);                   // p=0 initial; else slab free (end-bar)
    stageB(p);
    asm volatile("s_waitcnt vmcnt(0)" ::: "memory");
    __builtin_amdgcn_s_barrier();              // all waves' stages landed
    asm volatile("" ::: "memory");

    const int dh = (tap >= 6) ? 2 : (tap >= 3 ? 1 : 0);
    const int dw = tap - dh * 3;
    const char* Bb = lds + A_BYTES;
    __builtin_amdgcn_s_setprio(1);
#pragma unroll
    for (int kk = 0; kk < 2; ++kk) {
      const int ci_off = (kk << 5) + ((lane >> 4) << 3);
      bf16x8 av[4];
#pragma unroll
      for (int i = 0; i < 4; ++i) {
        const int pos = (wr + dh) * 66 + (i << 4) + l15 + dw;
        const int off = ((pos << 7) + (ci_off << 1)) ^ ((pos & 7) << 4);
        av[i] = *(const bf16x8*)(lds + off);
      }
#pragma unroll
      for (int j = 0; j < 4; ++j) {
        const bf16x8 bv = *(const bf16x8*)(Bb + boff[j][kk]);
#pragma unroll
        for (int i = 0; i < 4; ++i)
          acc[i][j] = __builtin_amdgcn_mfma_f32_16x16x32_bf16(av[i], bv, acc[i][j], 0, 0, 0);
      }
    }
    __builtin_amdgcn_s_setprio(0);
    asm volatile("" ::: "memory");
    __builtin_amdgcn_s_barrier();              // readers done -> slot/slab reusable
    asm volatile("" ::: "memory");

    if (++tap == 9) { tap = 0; ++s; }
  }

  // ---- epilogue: v = x+conv+beff, stats in-reg (f32), bf16 v via per-wave
  // LDS repack -> full-line 16B/lane stores (use_v16), else f32 to out.
  __syncthreads();
  float* lstat = (float*)(lds + A_BYTES + B_BYTES);   // 256 floats (sum128, sq128)
  if (tid < 256) lstat[tid] = 0.f;
  __syncthreads();

  char* wreg = lds + wid * 2048;               // this wave's repack region (16KB tot)
  const int wq = lane >> 4;                    // 0..3 (w quad group)
  const int ho = ho0 + wr;
  const int xorco = (l15 & 7) << 4;
#pragma unroll
  for (int j = 0; j < 4; ++j) {
    const int col = (wc << 6) + (j << 4) + l15;         // co_local 0..127
    const int cog = (ch << 7) + col;                    // global co
    const float be = beff[cog];
    const size_t base = ((((size_t)bb << 8) + (size_t)cog) << 12) + (ho << 6);
    float r1 = 0.f, r2 = 0.f;
#pragma unroll
    for (int i = 0; i < 4; ++i) {
      const int w0 = (i << 4) + (wq << 2);
      const float4 xv = *(const float4*)(x + base + w0);
      float4 v;
      v.x = acc[i][j][0] + xv.x + be;
      v.y = acc[i][j][1] + xv.y + be;
      v.z = acc[i][j][2] + xv.z + be;
      v.w = acc[i][j][3] + xv.w + be;
      r1 += v.x + v.y + v.z + v.w;
      r2 += v.x * v.x + v.y * v.y + v.z * v.z + v.w * v.w;
      if (use_v16) {
        union { __bf16 h[4]; uint64_t u64; } pk;
        pk.h[0] = (__bf16)v.x; pk.h[1] = (__bf16)v.y;
        pk.h[2] = (__bf16)v.z; pk.h[3] = (__bf16)v.w;
        const int wa = (l15 << 7) + (i << 5) + (wq << 3);
        *(uint64_t*)(wreg + (wa ^ xorco)) = pk.u64;
      } else {
        *(float4*)(out + base + w0) = v;
      }
    }
    r1 += __shfl_xor(r1, 16); r2 += __shfl_xor(r2, 16);
    r1 += __shfl_xor(r1, 32); r2 += __shfl_xor(r2, 32);
    if (lane < 16) {
      atomicAdd(&lstat[col], r1);
      atomicAdd(&lstat[128 + col], r2);
    }
    if (use_v16) {
      asm volatile("s_waitcnt lgkmcnt(0)" ::: "memory");   // wave's writes visible
#pragma unroll
      for (int t2 = 0; t2 < 2; ++t2) {
        const int co_r = lane >> 2;              // 0..15
        const int chk  = (lane & 3) + (t2 << 2); // 16B chunk = 8 w
        const int ra   = (co_r << 7) + (chk << 4);
        const uint4 pv = *(const uint4*)(wreg + (ra ^ ((co_r & 7) << 4)));
        const int co_g = (ch << 7) + (wc << 6) + (j << 4) + co_r;
        const size_t oi = ((((size_t)bb << 8) + (size_t)co_g) << 12) + (ho << 6) + (chk << 3);
        *(uint4*)(vout + oi) = pv;               // 16B x 4 lanes/co -> 64B lines
      }
      asm volatile("s_waitcnt lgkmcnt(0)" ::: "memory");   // reads done before next j
    }
  }
  __syncthreads();
  if (tid < 256) {
    const int c = tid & 127, part = tid >> 7;
    atomicAdd(&statsG[part * 256 + (ch << 7) + c], lstat[part * 128 + c]);
  }
}

// K3a: BN finalize + apply from bf16 v (NCHW) -> f32 out (grid-stride)
__global__ void k_apply_v16(const __bf16* __restrict__ v, float* __restrict__ out,
                            const float* __restrict__ statsG,
                            const float* __restrict__ gamma,
                            const float* __restrict__ beta) {
  __shared__ float ssc[256], ssh[256];
  const int t = threadIdx.x;    // 256
  {
    const float mean = statsG[t] * (1.f / 65536.f);
    const float var  = statsG[256 + t] * (1.f / 65536.f) - mean * mean;
    const float inv  = rsqrtf(var + 1e-5f);
    const float sc   = gamma[t] * inv;
    ssc[t] = sc;
    ssh[t] = beta[t] - mean * sc;
  }
  __syncthreads();
  const uint4* vp = (const uint4*)v;           // 8 bf16 per uint4
  for (size_t g = (size_t)blockIdx.x * 256 + t; g < 2097152ul; g += (size_t)gridDim.x * 256) {
    const int co = (int)((g >> 9) & 255);      // 512 chunks of 8 per (b,co) plane
    const uint4 pv = vp[g];
    const float sc = ssc[co], sh = ssh[co];
    float4 y0, y1;
    y0.x = __uint_as_float((pv.x & 0xffffu) << 16) * sc + sh;
    y0.y = __uint_as_float(pv.x & 0xffff0000u) * sc + sh;
    y0.z = __uint_as_float((pv.y & 0xffffu) << 16) * sc + sh;
    y0.w = __uint_as_float(pv.y & 0xffff0000u) * sc + sh;
    y1.x = __uint_as_float((pv.z & 0xffffu) << 16) * sc + sh;
    y1.y = __uint_as_float(pv.z & 0xffff0000u) * sc + sh;
    y1.z = __uint_as_float((pv.w & 0xffffu) << 16) * sc + sh;
    y1.w = __uint_as_float(pv.w & 0xffff0000u) * sc + sh;
    float4* op = (float4*)(out + g * 8);
    op[0] = y0;
    op[1] = y1;
  }
}

// K3b: fallback — BN finalize + in-place apply on f32 out
__global__ void k_apply_f32(float* __restrict__ out, const float* __restrict__ statsG,
                            const float* __restrict__ gamma,
                            const float* __restrict__ beta) {
  __shared__ float ssc[256], ssh[256];
  const int t = threadIdx.x;    // 256
  {
    const float mean = statsG[t] * (1.f / 65536.f);
    const float var  = statsG[256 + t] * (1.f / 65536.f) - mean * mean;
    const float inv  = rsqrtf(var + 1e-5f);
    const float sc   = gamma[t] * inv;
    ssc[t] = sc;
    ssh[t] = beta[t] - mean * sc;
  }
  __syncthreads();
  float4* op = (float4*)out;
  for (size_t g = (size_t)blockIdx.x * 256 + t; g < 4194304ul; g += (size_t)gridDim.x * 256) {
    const int co = (int)((g >> 10) & 255);
    float4 y = op[g];
    const float sc = ssc[co], sh = ssh[co];
    y.x = y.x * sc + sh; y.y = y.y * sc + sh;
    y.z = y.z * sc + sh; y.w = y.w * sc + sh;
    op[g] = y;
  }
}

extern "C" void kernel_launch(void* const* d_in, const int* in_sizes, int n_in,
                              void* d_out, int out_size, void* d_ws, size_t ws_size,
                              hipStream_t stream) {
  const float* x     = (const float*)d_in[0];
  const float* wall  = (const float*)d_in[1];
  const float* bias  = (const float*)d_in[2];
  const float* alpha = (const float*)d_in[3];
  const float* gamma = (const float*)d_in[4];
  const float* beta  = (const float*)d_in[5];
  float* out = (float*)d_out;

  char* ws = (char*)d_ws;
  __bf16* xT     = (__bf16*)(ws + XT_OFF);
  __bf16* Wt     = (__bf16*)(ws + WT_OFF);
  float*  beff   = (float*)(ws + BEFF_OFF);
  float*  zerob  = (float*)(ws + ZERO_OFF);
  float*  statsG = (float*)(ws + STATS_OFF);
  __bf16* vbuf   = (__bf16*)(ws + V_OFF);
  const int use_v16 = (ws_size >= WS_NEED) ? 1 : 0;

  k_prep<<<1280, 256, 0, stream>>>(wall, bias, alpha, Wt, beff, zerob, statsG, x, xT);
  k_conv<<<512, 512, 0, stream>>>(x, xT, Wt, beff, (const __bf16*)zerob, out,
                                  statsG, vbuf, use_v16);
  if (use_v16)
    k_apply_v16<<<2048, 256, 0, stream>>>(vbuf, out, statsG, gamma, beta);
  else
    k_apply_f32<<<2048, 256, 0, stream>>>(out, statsG, gamma, beta);
}